// Round 1
// baseline (3315.514 us; speedup 1.0000x reference)
//
#include <hip/hip_runtime.h>
#include <math.h>

#define DD 16
#define HH 64
#define WW 64
#define VV (DD*HH*WW)      // 65536
#define CC 64
#define NHEADS 4
#define NSAMP 8
#define HDIM 16

__device__ __forceinline__ float clampf(float v, float lo, float hi){ return fminf(fmaxf(v, lo), hi); }
__device__ __forceinline__ int imin(int a, int b){ return a < b ? a : b; }
__device__ __forceinline__ int imax(int a, int b){ return a > b ? a : b; }

// ---- weight repacks ------------------------------------------------------
// w[co][ci][tap] -> o[(ci*27+tap)*CO + co]   (contiguous over co for s_load_dwordx16)
__global__ void repack_w3(const float* __restrict__ w, float* __restrict__ o, int CO){
  int i = blockIdx.x*256 + threadIdx.x;
  int n = CO*CC*27;
  if (i >= n) return;
  int co = i / (CC*27);
  int r  = i - co*(CC*27);   // ci*27+tap
  o[r*CO + co] = w[i];
}
// out_w[co][ci] -> o[ci*64+co]
__global__ void repack_w1(const float* __restrict__ w, float* __restrict__ o){
  int i = blockIdx.x*256 + threadIdx.x; // 4096
  int co = i >> 6, ci = i & 63;
  o[ci*64 + co] = w[i];
}

// ---- kv 1x1 conv: mid_feat -> vols[head][z][y][x][32] --------------------
__global__ __launch_bounds__(256) void kv_kernel(const float* __restrict__ x,
    const float* __restrict__ kvw, const float* __restrict__ kvb,
    float* __restrict__ vols){
  int v = blockIdx.x*256 + threadIdx.x;
  float xr[CC];
  #pragma unroll
  for (int ci=0; ci<CC; ci++) xr[ci] = x[ci*VV + v];
  #pragma unroll 1
  for (int m=0; m<NHEADS; m++){
    #pragma unroll 1
    for (int g=0; g<8; g++){
      int ch0 = m*32 + g*4;
      float a0=kvb[ch0], a1=kvb[ch0+1], a2=kvb[ch0+2], a3=kvb[ch0+3];
      #pragma unroll
      for (int ci=0; ci<CC; ci++){
        float xv = xr[ci];
        a0 += kvw[(ch0  )*CC+ci]*xv;
        a1 += kvw[(ch0+1)*CC+ci]*xv;
        a2 += kvw[(ch0+2)*CC+ci]*xv;
        a3 += kvw[(ch0+3)*CC+ci]*xv;
      }
      float4 st = make_float4(a0,a1,a2,a3);
      *reinterpret_cast<float4*>(&vols[((size_t)m*VV + v)*32 + g*4]) = st;
    }
  }
}

// ---- q 1x1 conv (scaled by HD^-0.5) -> qbuf[co][v] -----------------------
__global__ __launch_bounds__(256) void q_kernel(const float* __restrict__ x,
    const float* __restrict__ qw, const float* __restrict__ qb,
    float* __restrict__ qbuf){
  int v = blockIdx.x*256 + threadIdx.x;
  float xr[CC];
  #pragma unroll
  for (int ci=0; ci<CC; ci++) xr[ci] = x[ci*VV + v];
  #pragma unroll 1
  for (int g=0; g<16; g++){
    int co0 = g*4;
    float a0=qb[co0], a1=qb[co0+1], a2=qb[co0+2], a3=qb[co0+3];
    #pragma unroll
    for (int ci=0; ci<CC; ci++){
      float xv = xr[ci];
      a0 += qw[(co0  )*CC+ci]*xv;
      a1 += qw[(co0+1)*CC+ci]*xv;
      a2 += qw[(co0+2)*CC+ci]*xv;
      a3 += qw[(co0+3)*CC+ci]*xv;
    }
    qbuf[(co0  )*VV+v]=a0*0.25f;
    qbuf[(co0+1)*VV+v]=a1*0.25f;
    qbuf[(co0+2)*VV+v]=a2*0.25f;
    qbuf[(co0+3)*VV+v]=a3*0.25f;
  }
}

// ---- 3x3x3 conv, pad=1, NCDHW in -> NCDHW out, fused activation ----------
// ACT 0: +bias then exact gelu.  ACT 1: tanh (no bias).
// Tile: 2(z) x 8(y) x 8(x) = 128 voxels; 256 threads = 128 vox * 2 co-groups.
template<int CO, int ACT>
__global__ __launch_bounds__(256) void conv3_kernel(const float* __restrict__ x,
    const float* __restrict__ wpk, const float* __restrict__ bias,
    float* __restrict__ out){
  constexpr int GRP = CO/2;
  __shared__ float xs[8][400];     // 8 ci x (4*10*10) halo
  int t = threadIdx.x;
  int vox = t & 127;
  int grp = __builtin_amdgcn_readfirstlane(t >> 7);   // wave-uniform
  int bx = blockIdx.x*8, by = blockIdx.y*8, bz = blockIdx.z*2;
  int vz = vox >> 6, vy = (vox >> 3) & 7, vx = vox & 7;
  float acc[GRP];
  #pragma unroll
  for (int i=0;i<GRP;i++) acc[i]=0.f;
  #pragma unroll 1
  for (int cc=0; cc<8; cc++){
    __syncthreads();
    for (int i=t; i<3200; i+=256){
      int ci = i/400; int hv = i - ci*400;
      int dz = hv/100; int r = hv - dz*100; int dy = r/10; int dx = r - dy*10;
      int gz = bz + dz - 1, gy = by + dy - 1, gx = bx + dx - 1;
      float val = 0.f;
      if (gz>=0 && gz<DD && gy>=0 && gy<HH && gx>=0 && gx<WW)
        val = x[(cc*8+ci)*VV + (gz*HH + gy)*WW + gx];
      xs[ci][hv] = val;
    }
    __syncthreads();
    #pragma unroll 1
    for (int ci=0; ci<8; ci++){
      #pragma unroll
      for (int kz=0; kz<3; kz++)
      #pragma unroll
      for (int ky=0; ky<3; ky++)
      #pragma unroll
      for (int kx=0; kx<3; kx++){
        float xv = xs[ci][(vz+kz)*100 + (vy+ky)*10 + (vx+kx)];
        const float* wp = wpk + ((cc*8+ci)*27 + (kz*9+ky*3+kx))*CO + grp*GRP;
        #pragma unroll
        for (int co=0; co<GRP; co++) acc[co] += wp[co]*xv;
      }
    }
  }
  int gvox = ((bz+vz)*HH + (by+vy))*WW + (bx+vx);
  #pragma unroll
  for (int co=0; co<GRP; co++){
    int oc = grp*GRP + co;
    float vvv = acc[co];
    if (ACT == 0){
      vvv += bias[oc];
      vvv = 0.5f*vvv*(1.f + erff(vvv*0.70710678118654752f));
    } else {
      vvv = tanhf(vvv);
    }
    out[oc*VV + gvox] = vvv;
  }
}

// ---- sampling geometry (replicates the reference's channel->axis swap) ---
struct Geom { int x0,x1,y0,y1,z0,z1; float wx,wy,wz; };
__device__ __forceinline__ Geom make_geom(float zb, float yb, float xb,
                                          float o0, float o1, float o2){
  // grid ch0 = zbase + o0/16 -> ix (*63); ch1 = ybase + o1/64 -> iy (*63);
  // ch2 = xbase + o2/64 -> iz (*15)
  float g0 = clampf(zb + o0*(1.f/16.f), -1.f, 1.f);
  float g1 = clampf(yb + o1*(1.f/64.f), -1.f, 1.f);
  float g2 = clampf(xb + o2*(1.f/64.f), -1.f, 1.f);
  float ix = (g0+1.f)*0.5f*63.f;
  float iy = (g1+1.f)*0.5f*63.f;
  float iz = (g2+1.f)*0.5f*15.f;
  float fx=floorf(ix), fy=floorf(iy), fz=floorf(iz);
  Geom g;
  g.wx = ix-fx; g.wy = iy-fy; g.wz = iz-fz;
  g.x0 = imin(imax((int)fx,0), WW-1); g.x1 = imin(g.x0+1, WW-1);
  g.y0 = imin(imax((int)fy,0), HH-1); g.y1 = imin(g.y0+1, HH-1);
  g.z0 = imin(imax((int)fz,0), DD-1); g.z1 = imin(g.z0+1, DD-1);
  return g;
}

// ---- sample + attention + out 1x1 conv + BN + relu -----------------------
// block: 64 voxels x 4 heads
__global__ __launch_bounds__(256) void sample_attn_kernel(
    const float* __restrict__ qbuf, const float* __restrict__ offbuf,
    const float* __restrict__ vols, const float* __restrict__ wout,
    const float* __restrict__ outb, const float* __restrict__ bng,
    const float* __restrict__ bnb, const float* __restrict__ bnm,
    const float* __restrict__ bnv, float* __restrict__ dout, int choff)
{
  __shared__ float fs[64*65];
  int t = threadIdx.x;
  int lv = t & 63;
  int m = __builtin_amdgcn_readfirstlane(t >> 6);
  int v = blockIdx.x*64 + lv;
  int z = v >> 12, y = (v >> 6) & 63, x = v & 63;
  float zb = -1.f + (float)z*(2.f/15.f);
  float yb = -1.f + (float)y*(2.f/63.f);
  float xb = -1.f + (float)x*(2.f/63.f);
  float q[HDIM];
  #pragma unroll
  for (int c=0;c<HDIM;c++) q[c] = qbuf[(m*HDIM+c)*VV + v];
  const float* vol = vols + (size_t)m*VV*32;
  float logit[NSAMP];
  #pragma unroll 1
  for (int s=0;s<NSAMP;s++){
    float o0 = offbuf[(m*24 + s*3 + 0)*VV + v];
    float o1 = offbuf[(m*24 + s*3 + 1)*VV + v];
    float o2 = offbuf[(m*24 + s*3 + 2)*VV + v];
    Geom g = make_geom(zb,yb,xb,o0,o1,o2);
    float lg = 0.f;
    #pragma unroll
    for (int kz=0;kz<2;kz++)
    #pragma unroll
    for (int ky=0;ky<2;ky++)
    #pragma unroll
    for (int kx=0;kx<2;kx++){
      int cz = kz? g.z1:g.z0, cy = ky? g.y1:g.y0, cx = kx? g.x1:g.x0;
      float cw = (kz? g.wz : 1.f-g.wz)*(ky? g.wy : 1.f-g.wy)*(kx? g.wx : 1.f-g.wx);
      const float4* cp = reinterpret_cast<const float4*>(vol + (size_t)((cz*HH+cy)*WW+cx)*32);
      float dotv = 0.f;
      #pragma unroll
      for (int c4=0;c4<4;c4++){
        float4 kvv = cp[c4];
        dotv += q[c4*4+0]*kvv.x + q[c4*4+1]*kvv.y + q[c4*4+2]*kvv.z + q[c4*4+3]*kvv.w;
      }
      lg += cw*dotv;
    }
    logit[s]=lg;
  }
  float mx = logit[0];
  #pragma unroll
  for (int s=1;s<NSAMP;s++) mx = fmaxf(mx, logit[s]);
  float ssum=0.f;
  #pragma unroll
  for (int s=0;s<NSAMP;s++){ logit[s]=expf(logit[s]-mx); ssum+=logit[s]; }
  float isum = 1.f/ssum;
  float fused[HDIM];
  #pragma unroll
  for (int c=0;c<HDIM;c++) fused[c]=0.f;
  #pragma unroll 1
  for (int s=0;s<NSAMP;s++){
    float attn = logit[s]*isum;
    float o0 = offbuf[(m*24 + s*3 + 0)*VV + v];
    float o1 = offbuf[(m*24 + s*3 + 1)*VV + v];
    float o2 = offbuf[(m*24 + s*3 + 2)*VV + v];
    Geom g = make_geom(zb,yb,xb,o0,o1,o2);
    #pragma unroll
    for (int kz=0;kz<2;kz++)
    #pragma unroll
    for (int ky=0;ky<2;ky++)
    #pragma unroll
    for (int kx=0;kx<2;kx++){
      int cz = kz? g.z1:g.z0, cy = ky? g.y1:g.y0, cx = kx? g.x1:g.x0;
      float cw = (kz? g.wz : 1.f-g.wz)*(ky? g.wy : 1.f-g.wy)*(kx? g.wx : 1.f-g.wx);
      float aw = attn*cw;
      const float4* cp = reinterpret_cast<const float4*>(vol + (size_t)((cz*HH+cy)*WW+cx)*32 + 16);
      #pragma unroll
      for (int c4=0;c4<4;c4++){
        float4 kvv = cp[c4];
        fused[c4*4+0] += aw*kvv.x;
        fused[c4*4+1] += aw*kvv.y;
        fused[c4*4+2] += aw*kvv.z;
        fused[c4*4+3] += aw*kvv.w;
      }
    }
  }
  #pragma unroll
  for (int c=0;c<HDIM;c++) fs[lv*65 + m*HDIM + c] = fused[c];
  __syncthreads();
  // out 1x1 conv: thread (lv, m) computes co = m*16 .. m*16+15 for voxel lv
  float acc[16];
  #pragma unroll
  for (int k=0;k<16;k++) acc[k]=0.f;
  #pragma unroll 1
  for (int ci=0; ci<CC; ci++){
    float xv = fs[lv*65 + ci];
    const float* wp = wout + ci*CC + m*16;
    #pragma unroll
    for (int k=0;k<16;k++) acc[k] += wp[k]*xv;
  }
  #pragma unroll
  for (int k=0;k<16;k++){
    int co = m*16 + k;
    float vvv = acc[k] + outb[co];
    vvv = (vvv - bnm[co]) * rsqrtf(bnv[co] + 1e-5f) * bng[co] + bnb[co];
    vvv = fmaxf(vvv, 0.f);
    dout[(size_t)(choff+co)*VV + v] = vvv;
  }
}

extern "C" void kernel_launch(void* const* d_in, const int* in_sizes, int n_in,
                              void* d_out, int out_size, void* d_ws, size_t ws_size,
                              hipStream_t stream){
  (void)in_sizes; (void)n_in; (void)out_size; (void)ws_size;
  const float* mid  = (const float*)d_in[0];
  const float* occ  = (const float*)d_in[1];
  const float* prev = (const float*)d_in[2];
  const float* off1w= (const float*)d_in[3];
  const float* off1b= (const float*)d_in[4];
  const float* off2w= (const float*)d_in[5];
  const float* kvw  = (const float*)d_in[6];
  const float* kvb  = (const float*)d_in[7];
  const float* qw   = (const float*)d_in[8];
  const float* qb   = (const float*)d_in[9];
  const float* outw = (const float*)d_in[10];
  const float* outb = (const float*)d_in[11];
  const float* bng  = (const float*)d_in[12];
  const float* bnb  = (const float*)d_in[13];
  const float* bnm  = (const float*)d_in[14];
  const float* bnv  = (const float*)d_in[15];
  float* out = (float*)d_out;
  float* ws  = (float*)d_ws;

  float* vols   = ws;                              // 4*V*32   = 8388608 f
  float* qbuf   = vols   + (size_t)4*VV*32;        // 64*V     = 4194304 f
  float* o1buf  = qbuf   + (size_t)CC*VV;          // 64*V     = 4194304 f
  float* offbuf = o1buf  + (size_t)CC*VV;          // 96*V     = 6291456 f
  float* wpk1   = offbuf + (size_t)96*VV;          // 110592 f
  float* wpk2   = wpk1   + 64*1728;                // 165888 f
  float* wpko   = wpk2   + 96*1728;                // 4096 f

  repack_w3<<<(64*1728+255)/256, 256, 0, stream>>>(off1w, wpk1, 64);
  repack_w3<<<(96*1728+255)/256, 256, 0, stream>>>(off2w, wpk2, 96);
  repack_w1<<<16, 256, 0, stream>>>(outw, wpko);
  kv_kernel<<<VV/256, 256, 0, stream>>>(mid, kvw, kvb, vols);
  hipMemcpyAsync(out, mid, (size_t)CC*VV*sizeof(float), hipMemcpyDeviceToDevice, stream);

  const float* currs[2] = {occ, prev};
  for (int call=0; call<2; call++){
    const float* cur = currs[call];
    q_kernel<<<VV/256, 256, 0, stream>>>(cur, qw, qb, qbuf);
    dim3 cgrid(WW/8, HH/8, DD/2);
    conv3_kernel<64,0><<<cgrid, 256, 0, stream>>>(cur, wpk1, off1b, o1buf);
    conv3_kernel<96,1><<<cgrid, 256, 0, stream>>>(o1buf, wpk2, off1b, offbuf);
    sample_attn_kernel<<<VV/64, 256, 0, stream>>>(qbuf, offbuf, vols, wpko,
        outb, bng, bnb, bnm, bnv, out, 64 + call*64);
  }
}

// Round 2
// 2303.163 us; speedup vs baseline: 1.4395x; 1.4395x over previous
//
#include <hip/hip_runtime.h>
#include <math.h>

#define DD 16
#define HH 64
#define WW 64
#define VV (DD*HH*WW)      // 65536
#define CC 64
#define NHEADS 4
#define NSAMP 8
#define HDIM 16

__device__ __forceinline__ float clampf(float v, float lo, float hi){ return fminf(fmaxf(v, lo), hi); }
__device__ __forceinline__ int imin(int a, int b){ return a < b ? a : b; }
__device__ __forceinline__ int imax(int a, int b){ return a > b ? a : b; }

// ---- weight repacks ------------------------------------------------------
// w[co][ci][tap] -> o[(ci*27+tap)*CO + co]   (contiguous over co, wave-uniform)
__global__ void repack_w3(const float* __restrict__ w, float* __restrict__ o, int CO){
  int i = blockIdx.x*256 + threadIdx.x;
  int n = CO*CC*27;
  if (i >= n) return;
  int co = i / (CC*27);
  int r  = i - co*(CC*27);   // ci*27+tap
  o[r*CO + co] = w[i];
}
// out_w[co][ci] -> o[ci*64+co]
__global__ void repack_w1(const float* __restrict__ w, float* __restrict__ o){
  int i = blockIdx.x*256 + threadIdx.x; // 4096
  int co = i >> 6, ci = i & 63;
  o[ci*64 + co] = w[i];
}

// ---- kv 1x1 conv: mid_feat -> vols[head][z][y][x][32] --------------------
__global__ __launch_bounds__(256) void kv_kernel(const float* __restrict__ x,
    const float* __restrict__ kvw, const float* __restrict__ kvb,
    float* __restrict__ vols){
  int v = blockIdx.x*256 + threadIdx.x;
  float xr[CC];
  #pragma unroll
  for (int ci=0; ci<CC; ci++) xr[ci] = x[ci*VV + v];
  #pragma unroll 1
  for (int m=0; m<NHEADS; m++){
    #pragma unroll 1
    for (int g=0; g<8; g++){
      int ch0 = m*32 + g*4;
      float a0=kvb[ch0], a1=kvb[ch0+1], a2=kvb[ch0+2], a3=kvb[ch0+3];
      #pragma unroll
      for (int ci=0; ci<CC; ci++){
        float xv = xr[ci];
        a0 += kvw[(ch0  )*CC+ci]*xv;
        a1 += kvw[(ch0+1)*CC+ci]*xv;
        a2 += kvw[(ch0+2)*CC+ci]*xv;
        a3 += kvw[(ch0+3)*CC+ci]*xv;
      }
      float4 st = make_float4(a0,a1,a2,a3);
      *reinterpret_cast<float4*>(&vols[((size_t)m*VV + v)*32 + g*4]) = st;
    }
  }
}

// ---- q 1x1 conv (scaled by HD^-0.5) -> qbuf[co][v] -----------------------
__global__ __launch_bounds__(256) void q_kernel(const float* __restrict__ x,
    const float* __restrict__ qw, const float* __restrict__ qb,
    float* __restrict__ qbuf){
  int v = blockIdx.x*256 + threadIdx.x;
  float xr[CC];
  #pragma unroll
  for (int ci=0; ci<CC; ci++) xr[ci] = x[ci*VV + v];
  #pragma unroll 1
  for (int g=0; g<16; g++){
    int co0 = g*4;
    float a0=qb[co0], a1=qb[co0+1], a2=qb[co0+2], a3=qb[co0+3];
    #pragma unroll
    for (int ci=0; ci<CC; ci++){
      float xv = xr[ci];
      a0 += qw[(co0  )*CC+ci]*xv;
      a1 += qw[(co0+1)*CC+ci]*xv;
      a2 += qw[(co0+2)*CC+ci]*xv;
      a3 += qw[(co0+3)*CC+ci]*xv;
    }
    qbuf[(co0  )*VV+v]=a0*0.25f;
    qbuf[(co0+1)*VV+v]=a1*0.25f;
    qbuf[(co0+2)*VV+v]=a2*0.25f;
    qbuf[(co0+3)*VV+v]=a3*0.25f;
  }
}

// ---- 3x3x3 conv, pad=1, NCDHW in -> NCDHW out, fused activation ----------
// ACT 0: +bias then exact gelu.  ACT 1: tanh (no bias).
// Tile: 1(z) x 8(y) x 8(x) = 64 voxels; 256 threads = 64 vox * 4 co-groups
// of CO/4 accumulators each (16 or 24 -> register-resident, no spill).
// LDS halo row stride padded to 12 -> exact 2-way bank aliasing (free).
template<int CO, int ACT>
__global__ __launch_bounds__(256) void conv3_kernel(const float* __restrict__ x,
    const float* __restrict__ wpk, const float* __restrict__ bias,
    float* __restrict__ out){
  constexpr int GRPC = CO/4;
  __shared__ float xs[8][3][120];     // 8 ci x 3 z-planes x (10 rows * 12 stride)
  int t = threadIdx.x;
  int vox = t & 63;
  int grp = __builtin_amdgcn_readfirstlane(t >> 6);   // wave-uniform
  int bx = blockIdx.x*8, by = blockIdx.y*8, z = blockIdx.z;
  int vy = vox >> 3, vx = vox & 7;
  float acc[GRPC];
  #pragma unroll
  for (int i=0;i<GRPC;i++) acc[i]=0.f;
  #pragma unroll 1
  for (int cc=0; cc<8; cc++){
    __syncthreads();
    // stage 8 ci x 3 x 10 x 10 = 2400 halo values with 256 threads
    for (int i=t; i<2400; i+=256){
      int ci = i/300; int hv = i - ci*300;
      int dz = hv/100; int r = hv - dz*100; int dy = r/10; int dx = r - dy*10;
      int gz = z + dz - 1, gy = by + dy - 1, gx = bx + dx - 1;
      float val = 0.f;
      if (gz>=0 && gz<DD && gy>=0 && gy<HH && gx>=0 && gx<WW)
        val = x[(cc*8+ci)*VV + (gz*HH + gy)*WW + gx];
      xs[ci][dz][dy*12+dx] = val;
    }
    __syncthreads();
    #pragma unroll 1
    for (int ci=0; ci<8; ci++){
      const float* wbase = wpk + (size_t)((cc*8+ci)*27)*CO + grp*GRPC;
      #pragma unroll
      for (int kz=0; kz<3; kz++)
      #pragma unroll
      for (int ky=0; ky<3; ky++)
      #pragma unroll
      for (int kx=0; kx<3; kx++){
        float xv = xs[ci][kz][(vy+ky)*12 + (vx+kx)];
        const float* wp = wbase + (kz*9+ky*3+kx)*CO;
        #pragma unroll
        for (int co=0; co<GRPC; co++) acc[co] += wp[co]*xv;
      }
    }
  }
  int gvox = (z*HH + (by+vy))*WW + (bx+vx);
  #pragma unroll
  for (int co=0; co<GRPC; co++){
    int oc = grp*GRPC + co;
    float vvv = acc[co];
    if (ACT == 0){
      vvv += bias[oc];
      vvv = 0.5f*vvv*(1.f + erff(vvv*0.70710678118654752f));
    } else {
      vvv = tanhf(vvv);
    }
    out[oc*VV + gvox] = vvv;
  }
}

// ---- sampling geometry (replicates the reference's channel->axis swap) ---
struct Geom { int x0,x1,y0,y1,z0,z1; float wx,wy,wz; };
__device__ __forceinline__ Geom make_geom(float zb, float yb, float xb,
                                          float o0, float o1, float o2){
  // grid ch0 = zbase + o0/16 -> ix (*63); ch1 = ybase + o1/64 -> iy (*63);
  // ch2 = xbase + o2/64 -> iz (*15)
  float g0 = clampf(zb + o0*(1.f/16.f), -1.f, 1.f);
  float g1 = clampf(yb + o1*(1.f/64.f), -1.f, 1.f);
  float g2 = clampf(xb + o2*(1.f/64.f), -1.f, 1.f);
  float ix = (g0+1.f)*0.5f*63.f;
  float iy = (g1+1.f)*0.5f*63.f;
  float iz = (g2+1.f)*0.5f*15.f;
  float fx=floorf(ix), fy=floorf(iy), fz=floorf(iz);
  Geom g;
  g.wx = ix-fx; g.wy = iy-fy; g.wz = iz-fz;
  g.x0 = imin(imax((int)fx,0), WW-1); g.x1 = imin(g.x0+1, WW-1);
  g.y0 = imin(imax((int)fy,0), HH-1); g.y1 = imin(g.y0+1, HH-1);
  g.z0 = imin(imax((int)fz,0), DD-1); g.z1 = imin(g.z0+1, DD-1);
  return g;
}

// ---- sample + attention + out 1x1 conv + BN + relu -----------------------
// block: 64 voxels x 4 heads
__global__ __launch_bounds__(256) void sample_attn_kernel(
    const float* __restrict__ qbuf, const float* __restrict__ offbuf,
    const float* __restrict__ vols, const float* __restrict__ wout,
    const float* __restrict__ outb, const float* __restrict__ bng,
    const float* __restrict__ bnb, const float* __restrict__ bnm,
    const float* __restrict__ bnv, float* __restrict__ dout, int choff)
{
  __shared__ float fs[64*65];
  int t = threadIdx.x;
  int lv = t & 63;
  int m = __builtin_amdgcn_readfirstlane(t >> 6);
  int v = blockIdx.x*64 + lv;
  int z = v >> 12, y = (v >> 6) & 63, x = v & 63;
  float zb = -1.f + (float)z*(2.f/15.f);
  float yb = -1.f + (float)y*(2.f/63.f);
  float xb = -1.f + (float)x*(2.f/63.f);
  float q[HDIM];
  #pragma unroll
  for (int c=0;c<HDIM;c++) q[c] = qbuf[(m*HDIM+c)*VV + v];
  const float* vol = vols + (size_t)m*VV*32;
  float logit[NSAMP];
  #pragma unroll 1
  for (int s=0;s<NSAMP;s++){
    float o0 = offbuf[(m*24 + s*3 + 0)*VV + v];
    float o1 = offbuf[(m*24 + s*3 + 1)*VV + v];
    float o2 = offbuf[(m*24 + s*3 + 2)*VV + v];
    Geom g = make_geom(zb,yb,xb,o0,o1,o2);
    float lg = 0.f;
    #pragma unroll
    for (int kz=0;kz<2;kz++)
    #pragma unroll
    for (int ky=0;ky<2;ky++)
    #pragma unroll
    for (int kx=0;kx<2;kx++){
      int cz = kz? g.z1:g.z0, cy = ky? g.y1:g.y0, cx = kx? g.x1:g.x0;
      float cw = (kz? g.wz : 1.f-g.wz)*(ky? g.wy : 1.f-g.wy)*(kx? g.wx : 1.f-g.wx);
      const float4* cp = reinterpret_cast<const float4*>(vol + (size_t)((cz*HH+cy)*WW+cx)*32);
      float dotv = 0.f;
      #pragma unroll
      for (int c4=0;c4<4;c4++){
        float4 kvv = cp[c4];
        dotv += q[c4*4+0]*kvv.x + q[c4*4+1]*kvv.y + q[c4*4+2]*kvv.z + q[c4*4+3]*kvv.w;
      }
      lg += cw*dotv;
    }
    logit[s]=lg;
  }
  float mx = logit[0];
  #pragma unroll
  for (int s=1;s<NSAMP;s++) mx = fmaxf(mx, logit[s]);
  float ssum=0.f;
  #pragma unroll
  for (int s=0;s<NSAMP;s++){ logit[s]=expf(logit[s]-mx); ssum+=logit[s]; }
  float isum = 1.f/ssum;
  float fused[HDIM];
  #pragma unroll
  for (int c=0;c<HDIM;c++) fused[c]=0.f;
  #pragma unroll 1
  for (int s=0;s<NSAMP;s++){
    float attn = logit[s]*isum;
    float o0 = offbuf[(m*24 + s*3 + 0)*VV + v];
    float o1 = offbuf[(m*24 + s*3 + 1)*VV + v];
    float o2 = offbuf[(m*24 + s*3 + 2)*VV + v];
    Geom g = make_geom(zb,yb,xb,o0,o1,o2);
    #pragma unroll
    for (int kz=0;kz<2;kz++)
    #pragma unroll
    for (int ky=0;ky<2;ky++)
    #pragma unroll
    for (int kx=0;kx<2;kx++){
      int cz = kz? g.z1:g.z0, cy = ky? g.y1:g.y0, cx = kx? g.x1:g.x0;
      float cw = (kz? g.wz : 1.f-g.wz)*(ky? g.wy : 1.f-g.wy)*(kx? g.wx : 1.f-g.wx);
      float aw = attn*cw;
      const float4* cp = reinterpret_cast<const float4*>(vol + (size_t)((cz*HH+cy)*WW+cx)*32 + 16);
      #pragma unroll
      for (int c4=0;c4<4;c4++){
        float4 kvv = cp[c4];
        fused[c4*4+0] += aw*kvv.x;
        fused[c4*4+1] += aw*kvv.y;
        fused[c4*4+2] += aw*kvv.z;
        fused[c4*4+3] += aw*kvv.w;
      }
    }
  }
  #pragma unroll
  for (int c=0;c<HDIM;c++) fs[lv*65 + m*HDIM + c] = fused[c];
  __syncthreads();
  // out 1x1 conv: thread (lv, m) computes co = m*16 .. m*16+15 for voxel lv
  float acc[16];
  #pragma unroll
  for (int k=0;k<16;k++) acc[k]=0.f;
  #pragma unroll 1
  for (int ci=0; ci<CC; ci++){
    float xv = fs[lv*65 + ci];
    const float* wp = wout + ci*CC + m*16;
    #pragma unroll
    for (int k=0;k<16;k++) acc[k] += wp[k]*xv;
  }
  #pragma unroll
  for (int k=0;k<16;k++){
    int co = m*16 + k;
    float vvv = acc[k] + outb[co];
    vvv = (vvv - bnm[co]) * rsqrtf(bnv[co] + 1e-5f) * bng[co] + bnb[co];
    vvv = fmaxf(vvv, 0.f);
    dout[(size_t)(choff+co)*VV + v] = vvv;
  }
}

extern "C" void kernel_launch(void* const* d_in, const int* in_sizes, int n_in,
                              void* d_out, int out_size, void* d_ws, size_t ws_size,
                              hipStream_t stream){
  (void)in_sizes; (void)n_in; (void)out_size; (void)ws_size;
  const float* mid  = (const float*)d_in[0];
  const float* occ  = (const float*)d_in[1];
  const float* prev = (const float*)d_in[2];
  const float* off1w= (const float*)d_in[3];
  const float* off1b= (const float*)d_in[4];
  const float* off2w= (const float*)d_in[5];
  const float* kvw  = (const float*)d_in[6];
  const float* kvb  = (const float*)d_in[7];
  const float* qw   = (const float*)d_in[8];
  const float* qb   = (const float*)d_in[9];
  const float* outw = (const float*)d_in[10];
  const float* outb = (const float*)d_in[11];
  const float* bng  = (const float*)d_in[12];
  const float* bnb  = (const float*)d_in[13];
  const float* bnm  = (const float*)d_in[14];
  const float* bnv  = (const float*)d_in[15];
  float* out = (float*)d_out;
  float* ws  = (float*)d_ws;

  float* vols   = ws;                              // 4*V*32   = 8388608 f
  float* qbuf   = vols   + (size_t)4*VV*32;        // 64*V     = 4194304 f
  float* o1buf  = qbuf   + (size_t)CC*VV;          // 64*V     = 4194304 f
  float* offbuf = o1buf  + (size_t)CC*VV;          // 96*V     = 6291456 f
  float* wpk1   = offbuf + (size_t)96*VV;          // 110592 f
  float* wpk2   = wpk1   + 64*1728;                // 165888 f
  float* wpko   = wpk2   + 96*1728;                // 4096 f

  repack_w3<<<(64*1728+255)/256, 256, 0, stream>>>(off1w, wpk1, 64);
  repack_w3<<<(96*1728+255)/256, 256, 0, stream>>>(off2w, wpk2, 96);
  repack_w1<<<16, 256, 0, stream>>>(outw, wpko);
  kv_kernel<<<VV/256, 256, 0, stream>>>(mid, kvw, kvb, vols);
  hipMemcpyAsync(out, mid, (size_t)CC*VV*sizeof(float), hipMemcpyDeviceToDevice, stream);

  const float* currs[2] = {occ, prev};
  for (int call=0; call<2; call++){
    const float* cur = currs[call];
    q_kernel<<<VV/256, 256, 0, stream>>>(cur, qw, qb, qbuf);
    dim3 cgrid(WW/8, HH/8, DD);
    conv3_kernel<64,0><<<cgrid, 256, 0, stream>>>(cur, wpk1, off1b, o1buf);
    conv3_kernel<96,1><<<cgrid, 256, 0, stream>>>(o1buf, wpk2, off1b, offbuf);
    sample_attn_kernel<<<VV/64, 256, 0, stream>>>(qbuf, offbuf, vols, wpko,
        outb, bng, bnb, bnm, bnv, out, 64 + call*64);
  }
}

// Round 3
// 1518.561 us; speedup vs baseline: 2.1833x; 1.5167x over previous
//
#include <hip/hip_runtime.h>
#include <math.h>

#define DD 16
#define HH 64
#define WW 64
#define VV (DD*HH*WW)      // 65536
#define CC 64
#define NHEADS 4
#define NSAMP 8
#define HDIM 16

typedef unsigned int uint;
typedef unsigned short ushort;

__device__ __forceinline__ float clampf(float v, float lo, float hi){ return fminf(fmaxf(v, lo), hi); }
__device__ __forceinline__ int imin(int a, int b){ return a < b ? a : b; }
__device__ __forceinline__ int imax(int a, int b){ return a > b ? a : b; }

// bf16 helpers (RNE)
__device__ __forceinline__ ushort f2bf(float f){
  uint u = __float_as_uint(f);
  uint r = (u + 0x7fffu + ((u>>16)&1u)) >> 16;
  return (ushort)r;
}
__device__ __forceinline__ uint packbf2(float a, float b){
  return (uint)f2bf(a) | ((uint)f2bf(b) << 16);
}
__device__ __forceinline__ float bflo(uint u){ return __uint_as_float(u << 16); }
__device__ __forceinline__ float bfhi(uint u){ return __uint_as_float(u & 0xffff0000u); }

__device__ __forceinline__ float dot8(uint4 k, const float* q){
  return q[0]*bflo(k.x)+q[1]*bfhi(k.x)+q[2]*bflo(k.y)+q[3]*bfhi(k.y)
       + q[4]*bflo(k.z)+q[5]*bfhi(k.z)+q[6]*bflo(k.w)+q[7]*bfhi(k.w);
}
__device__ __forceinline__ void acc8(uint4 u, float cw, float* val){
  val[0]+=cw*bflo(u.x); val[1]+=cw*bfhi(u.x);
  val[2]+=cw*bflo(u.y); val[3]+=cw*bfhi(u.y);
  val[4]+=cw*bflo(u.z); val[5]+=cw*bfhi(u.z);
  val[6]+=cw*bflo(u.w); val[7]+=cw*bfhi(u.w);
}

// ---- weight repacks ------------------------------------------------------
__global__ void repack_w3(const float* __restrict__ w, float* __restrict__ o, int CO){
  int i = blockIdx.x*256 + threadIdx.x;
  int n = CO*CC*27;
  if (i >= n) return;
  int co = i / (CC*27);
  int r  = i - co*(CC*27);   // ci*27+tap
  o[r*CO + co] = w[i];
}
__global__ void repack_w1(const float* __restrict__ w, float* __restrict__ o){
  int i = blockIdx.x*256 + threadIdx.x; // 4096
  int co = i >> 6, ci = i & 63;
  o[ci*64 + co] = w[i];
}

// ---- kv 1x1 conv: mid_feat -> bf16 vols[head][y][x][z][32ch] -------------
// 32 ch (16 key + 16 value) packed as 16 uints = 64 B per (head,voxel).
__global__ __launch_bounds__(256) void kv_kernel(const float* __restrict__ x,
    const float* __restrict__ kvw, const float* __restrict__ kvb,
    uint* __restrict__ vols){
  int v = blockIdx.x*256 + threadIdx.x;
  int z = v >> 12, y = (v >> 6) & 63, xx = v & 63;
  size_t widx = ((size_t)(y*WW + xx)*DD + z) * 16;
  float xr[CC];
  #pragma unroll
  for (int ci=0; ci<CC; ci++) xr[ci] = x[ci*VV + v];
  #pragma unroll 1
  for (int m=0; m<NHEADS; m++){
    float a[32];
    #pragma unroll 1
    for (int g=0; g<8; g++){
      int ch0 = m*32 + g*4;
      float a0=kvb[ch0], a1=kvb[ch0+1], a2=kvb[ch0+2], a3=kvb[ch0+3];
      #pragma unroll
      for (int ci=0; ci<CC; ci++){
        float xv = xr[ci];
        a0 += kvw[(ch0  )*CC+ci]*xv;
        a1 += kvw[(ch0+1)*CC+ci]*xv;
        a2 += kvw[(ch0+2)*CC+ci]*xv;
        a3 += kvw[(ch0+3)*CC+ci]*xv;
      }
      a[g*4+0]=a0; a[g*4+1]=a1; a[g*4+2]=a2; a[g*4+3]=a3;
    }
    uint4* dst = reinterpret_cast<uint4*>(vols + (size_t)m*VV*16 + widx);
    #pragma unroll
    for (int j=0; j<4; j++){
      uint4 p;
      p.x = packbf2(a[j*8+0], a[j*8+1]);
      p.y = packbf2(a[j*8+2], a[j*8+3]);
      p.z = packbf2(a[j*8+4], a[j*8+5]);
      p.w = packbf2(a[j*8+6], a[j*8+7]);
      dst[j] = p;
    }
  }
}

// ---- q 1x1 conv (scaled by HD^-0.5) -> qbuf[co][v] -----------------------
__global__ __launch_bounds__(256) void q_kernel(const float* __restrict__ x,
    const float* __restrict__ qw, const float* __restrict__ qb,
    float* __restrict__ qbuf){
  int v = blockIdx.x*256 + threadIdx.x;
  float xr[CC];
  #pragma unroll
  for (int ci=0; ci<CC; ci++) xr[ci] = x[ci*VV + v];
  #pragma unroll 1
  for (int g=0; g<16; g++){
    int co0 = g*4;
    float a0=qb[co0], a1=qb[co0+1], a2=qb[co0+2], a3=qb[co0+3];
    #pragma unroll
    for (int ci=0; ci<CC; ci++){
      float xv = xr[ci];
      a0 += qw[(co0  )*CC+ci]*xv;
      a1 += qw[(co0+1)*CC+ci]*xv;
      a2 += qw[(co0+2)*CC+ci]*xv;
      a3 += qw[(co0+3)*CC+ci]*xv;
    }
    qbuf[(co0  )*VV+v]=a0*0.25f;
    qbuf[(co0+1)*VV+v]=a1*0.25f;
    qbuf[(co0+2)*VV+v]=a2*0.25f;
    qbuf[(co0+3)*VV+v]=a3*0.25f;
  }
}

// ---- 3x3x3 conv, pad=1, NCDHW in -> NCDHW out, fused activation ----------
template<int CO, int ACT>
__global__ __launch_bounds__(256) void conv3_kernel(const float* __restrict__ x,
    const float* __restrict__ wpk, const float* __restrict__ bias,
    float* __restrict__ out){
  constexpr int GRPC = CO/4;
  __shared__ float xs[8][3][120];     // 8 ci x 3 z-planes x (10 rows * 12 stride)
  int t = threadIdx.x;
  int vox = t & 63;
  int grp = __builtin_amdgcn_readfirstlane(t >> 6);   // wave-uniform
  int bx = blockIdx.x*8, by = blockIdx.y*8, z = blockIdx.z;
  int vy = vox >> 3, vx = vox & 7;
  float acc[GRPC];
  #pragma unroll
  for (int i=0;i<GRPC;i++) acc[i]=0.f;
  #pragma unroll 1
  for (int cc=0; cc<8; cc++){
    __syncthreads();
    for (int i=t; i<2400; i+=256){
      int ci = i/300; int hv = i - ci*300;
      int dz = hv/100; int r = hv - dz*100; int dy = r/10; int dx = r - dy*10;
      int gz = z + dz - 1, gy = by + dy - 1, gx = bx + dx - 1;
      float val = 0.f;
      if (gz>=0 && gz<DD && gy>=0 && gy<HH && gx>=0 && gx<WW)
        val = x[(cc*8+ci)*VV + (gz*HH + gy)*WW + gx];
      xs[ci][dz][dy*12+dx] = val;
    }
    __syncthreads();
    #pragma unroll 1
    for (int ci=0; ci<8; ci++){
      const float* wbase = wpk + (size_t)((cc*8+ci)*27)*CO + grp*GRPC;
      #pragma unroll
      for (int kz=0; kz<3; kz++)
      #pragma unroll
      for (int ky=0; ky<3; ky++)
      #pragma unroll
      for (int kx=0; kx<3; kx++){
        float xv = xs[ci][kz][(vy+ky)*12 + (vx+kx)];
        const float* wp = wbase + (kz*9+ky*3+kx)*CO;
        #pragma unroll
        for (int co=0; co<GRPC; co++) acc[co] += wp[co]*xv;
      }
    }
  }
  int gvox = (z*HH + (by+vy))*WW + (bx+vx);
  #pragma unroll
  for (int co=0; co<GRPC; co++){
    int oc = grp*GRPC + co;
    float vvv = acc[co];
    if (ACT == 0){
      vvv += bias[oc];
      vvv = 0.5f*vvv*(1.f + erff(vvv*0.70710678118654752f));
    } else {
      vvv = tanhf(vvv);
    }
    out[oc*VV + gvox] = vvv;
  }
}

// ---- sampling geometry (replicates the reference's channel->axis swap) ---
struct Geom { int x0,x1,y0,y1,z0,z1; float wx,wy,wz; };
__device__ __forceinline__ Geom make_geom(float zb, float yb, float xb,
                                          float o0, float o1, float o2){
  float g0 = clampf(zb + o0*(1.f/16.f), -1.f, 1.f);
  float g1 = clampf(yb + o1*(1.f/64.f), -1.f, 1.f);
  float g2 = clampf(xb + o2*(1.f/64.f), -1.f, 1.f);
  float ix = (g0+1.f)*0.5f*63.f;
  float iy = (g1+1.f)*0.5f*63.f;
  float iz = (g2+1.f)*0.5f*15.f;
  float fx=floorf(ix), fy=floorf(iy), fz=floorf(iz);
  Geom g;
  g.wx = ix-fx; g.wy = iy-fy; g.wz = iz-fz;
  g.x0 = imin(imax((int)fx,0), WW-1); g.x1 = imin(g.x0+1, WW-1);
  g.y0 = imin(imax((int)fy,0), HH-1); g.y1 = imin(g.y0+1, HH-1);
  g.z0 = imin(imax((int)fz,0), DD-1); g.z1 = imin(g.z0+1, DD-1);
  return g;
}

// ---- sample + attention (online softmax, single pass) + out conv + BN ----
// block: 64 voxels (one x-row) x 4 heads (one wave per head)
__global__ __launch_bounds__(256) void sample_attn_kernel(
    const float* __restrict__ qbuf, const float* __restrict__ offbuf,
    const uint* __restrict__ vols, const float* __restrict__ wout,
    const float* __restrict__ outb, const float* __restrict__ bng,
    const float* __restrict__ bnb, const float* __restrict__ bnm,
    const float* __restrict__ bnv, float* __restrict__ dout, int choff)
{
  __shared__ float fs[64*65];
  int t = threadIdx.x;
  int lv = t & 63;
  int m = __builtin_amdgcn_readfirstlane(t >> 6);
  int bid = blockIdx.x;
  int r = ((bid & 7) << 7) | (bid >> 3);      // XCD-slab swizzle: XCD i -> z in {2i,2i+1}
  int v = r*64 + lv;
  int z = v >> 12, y = (v >> 6) & 63, x = v & 63;
  float zb = -1.f + (float)z*(2.f/15.f);
  float yb = -1.f + (float)y*(2.f/63.f);
  float xb = -1.f + (float)x*(2.f/63.f);
  float q[HDIM];
  #pragma unroll
  for (int c=0;c<HDIM;c++) q[c] = qbuf[(m*HDIM+c)*VV + v];
  const uint* vol = vols + (size_t)m*VV*16;
  float mrun = -1e30f, lrun = 0.f;
  float fused[HDIM];
  #pragma unroll
  for (int c=0;c<HDIM;c++) fused[c]=0.f;
  #pragma unroll 1
  for (int s=0;s<NSAMP;s++){
    float o0 = offbuf[(m*24 + s*3 + 0)*VV + v];
    float o1 = offbuf[(m*24 + s*3 + 1)*VV + v];
    float o2 = offbuf[(m*24 + s*3 + 2)*VV + v];
    Geom g = make_geom(zb,yb,xb,o0,o1,o2);
    float lg = 0.f;
    float val[HDIM];
    #pragma unroll
    for (int c=0;c<HDIM;c++) val[c]=0.f;
    #pragma unroll
    for (int ky=0;ky<2;ky++)
    #pragma unroll
    for (int kx=0;kx<2;kx++){
      int cy = ky? g.y1:g.y0, cx = kx? g.x1:g.x0;
      float wyx = (ky? g.wy : 1.f-g.wy)*(kx? g.wx : 1.f-g.wx);
      size_t base = (size_t)(cy*WW + cx)*DD;
      #pragma unroll
      for (int kz=0;kz<2;kz++){
        int cz = kz? g.z1:g.z0;
        float cw = wyx * (kz? g.wz : 1.f-g.wz);
        const uint4* cp = reinterpret_cast<const uint4*>(vol + (base + cz)*16);
        uint4 k0 = cp[0], k1 = cp[1];      // key ch 0..15
        uint4 v0 = cp[2], v1 = cp[3];      // value ch 0..15
        lg += cw*(dot8(k0, q) + dot8(k1, q+8));
        acc8(v0, cw, val);
        acc8(v1, cw, val+8);
      }
    }
    // online softmax update
    float mnew = fmaxf(mrun, lg);
    float sc = expf(mrun - mnew);
    float e  = expf(lg - mnew);
    lrun = lrun*sc + e;
    #pragma unroll
    for (int c=0;c<HDIM;c++) fused[c] = fused[c]*sc + e*val[c];
    mrun = mnew;
  }
  float isum = 1.f/lrun;
  #pragma unroll
  for (int c=0;c<HDIM;c++) fs[lv*65 + m*HDIM + c] = fused[c]*isum;
  __syncthreads();
  // out 1x1 conv: thread (lv, m) computes co = m*16 .. m*16+15 for voxel lv
  float acc[16];
  #pragma unroll
  for (int k=0;k<16;k++) acc[k]=0.f;
  #pragma unroll 1
  for (int ci=0; ci<CC; ci++){
    float xv = fs[lv*65 + ci];
    const float* wp = wout + ci*CC + m*16;
    #pragma unroll
    for (int k=0;k<16;k++) acc[k] += wp[k]*xv;
  }
  #pragma unroll
  for (int k=0;k<16;k++){
    int co = m*16 + k;
    float vvv = acc[k] + outb[co];
    vvv = (vvv - bnm[co]) * rsqrtf(bnv[co] + 1e-5f) * bng[co] + bnb[co];
    vvv = fmaxf(vvv, 0.f);
    dout[(size_t)(choff+co)*VV + v] = vvv;
  }
}

extern "C" void kernel_launch(void* const* d_in, const int* in_sizes, int n_in,
                              void* d_out, int out_size, void* d_ws, size_t ws_size,
                              hipStream_t stream){
  (void)in_sizes; (void)n_in; (void)out_size; (void)ws_size;
  const float* mid  = (const float*)d_in[0];
  const float* occ  = (const float*)d_in[1];
  const float* prev = (const float*)d_in[2];
  const float* off1w= (const float*)d_in[3];
  const float* off1b= (const float*)d_in[4];
  const float* off2w= (const float*)d_in[5];
  const float* kvw  = (const float*)d_in[6];
  const float* kvb  = (const float*)d_in[7];
  const float* qw   = (const float*)d_in[8];
  const float* qb   = (const float*)d_in[9];
  const float* outw = (const float*)d_in[10];
  const float* outb = (const float*)d_in[11];
  const float* bng  = (const float*)d_in[12];
  const float* bnb  = (const float*)d_in[13];
  const float* bnm  = (const float*)d_in[14];
  const float* bnv  = (const float*)d_in[15];
  float* out = (float*)d_out;
  float* ws  = (float*)d_ws;

  uint*  vols   = (uint*)ws;                       // 4*V*16 uints = 16.8 MB
  float* qbuf   = ws     + (size_t)4*VV*16;        // 64*V floats
  float* o1buf  = qbuf   + (size_t)CC*VV;          // 64*V floats
  float* offbuf = o1buf  + (size_t)CC*VV;          // 96*V floats
  float* wpk1   = offbuf + (size_t)96*VV;          // 110592 f
  float* wpk2   = wpk1   + 64*1728;                // 165888 f
  float* wpko   = wpk2   + 96*1728;                // 4096 f

  repack_w3<<<(64*1728+255)/256, 256, 0, stream>>>(off1w, wpk1, 64);
  repack_w3<<<(96*1728+255)/256, 256, 0, stream>>>(off2w, wpk2, 96);
  repack_w1<<<16, 256, 0, stream>>>(outw, wpko);
  kv_kernel<<<VV/256, 256, 0, stream>>>(mid, kvw, kvb, vols);
  hipMemcpyAsync(out, mid, (size_t)CC*VV*sizeof(float), hipMemcpyDeviceToDevice, stream);

  const float* currs[2] = {occ, prev};
  for (int call=0; call<2; call++){
    const float* cur = currs[call];
    q_kernel<<<VV/256, 256, 0, stream>>>(cur, qw, qb, qbuf);
    dim3 cgrid(WW/8, HH/8, DD);
    conv3_kernel<64,0><<<cgrid, 256, 0, stream>>>(cur, wpk1, off1b, o1buf);
    conv3_kernel<96,1><<<cgrid, 256, 0, stream>>>(o1buf, wpk2, off1b, offbuf);
    sample_attn_kernel<<<VV/64, 256, 0, stream>>>(qbuf, offbuf, vols, wpko,
        outb, bng, bnb, bnm, bnv, out, 64 + call*64);
  }
}

// Round 4
// 658.448 us; speedup vs baseline: 5.0353x; 2.3063x over previous
//
#include <hip/hip_runtime.h>
#include <math.h>

#define DD 16
#define HH 64
#define WW 64
#define VV (DD*HH*WW)      // 65536
#define CC 64
#define NHEADS 4
#define NSAMP 8
#define HDIM 16

typedef unsigned int uint;
typedef unsigned short ushort;
typedef __attribute__((ext_vector_type(8))) short bf16x8;
typedef __attribute__((ext_vector_type(4))) float f32x4;

__device__ __forceinline__ float clampf(float v, float lo, float hi){ return fminf(fmaxf(v, lo), hi); }
__device__ __forceinline__ int imin(int a, int b){ return a < b ? a : b; }
__device__ __forceinline__ int imax(int a, int b){ return a > b ? a : b; }

// bf16 helpers (RNE)
__device__ __forceinline__ ushort f2bf(float f){
  uint u = __float_as_uint(f);
  uint r = (u + 0x7fffu + ((u>>16)&1u)) >> 16;
  return (ushort)r;
}
__device__ __forceinline__ uint packbf2(float a, float b){
  return (uint)f2bf(a) | ((uint)f2bf(b) << 16);
}
__device__ __forceinline__ float bflo(uint u){ return __uint_as_float(u << 16); }
__device__ __forceinline__ float bfhi(uint u){ return __uint_as_float(u & 0xffff0000u); }

__device__ __forceinline__ float dot8(uint4 k, const float* q){
  return q[0]*bflo(k.x)+q[1]*bfhi(k.x)+q[2]*bflo(k.y)+q[3]*bfhi(k.y)
       + q[4]*bflo(k.z)+q[5]*bfhi(k.z)+q[6]*bflo(k.w)+q[7]*bfhi(k.w);
}
__device__ __forceinline__ void acc8(uint4 u, float cw, float* val){
  val[0]+=cw*bflo(u.x); val[1]+=cw*bfhi(u.x);
  val[2]+=cw*bflo(u.y); val[3]+=cw*bfhi(u.y);
  val[4]+=cw*bflo(u.z); val[5]+=cw*bfhi(u.z);
  val[6]+=cw*bflo(u.w); val[7]+=cw*bfhi(u.w);
}

// ---- weight repacks ------------------------------------------------------
// 3x3x3 conv weights -> bf16 pairs in exact MFMA A-fragment order.
// K ordering: k = tap*64 + ci; K-step s (32 wide): tap=s>>1, h=s&1,
// ci = h*32 + q*8 + j.  Fragment layout: lane = q*16+m holds A[co=g*16+m][8 k].
// uint index U = (((s*MG+g)*4+q)*16+m)*4 + j2  (j=2*j2, 2*j2+1)
__global__ void repack_wmfma(const float* __restrict__ w, uint* __restrict__ o, int MG){
  int U = blockIdx.x*256 + threadIdx.x;
  int total = 54*MG*256;
  if (U >= total) return;
  int j2 = U & 3;
  int m  = (U>>2) & 15;
  int q  = (U>>6) & 3;
  int rest = U >> 8;          // s*MG + g
  int g = rest % MG;
  int s = rest / MG;
  int tap = s >> 1, h = s & 1;
  int co = g*16 + m;
  int ci = h*32 + q*8 + j2*2;
  int base = co*1728 + ci*27 + tap;
  o[U] = packbf2(w[base], w[base + 27]);
}
// out_w[co][ci] -> o[ci*64+co]
__global__ void repack_w1(const float* __restrict__ w, float* __restrict__ o){
  int i = blockIdx.x*256 + threadIdx.x; // 4096
  int co = i >> 6, ci = i & 63;
  o[ci*64 + co] = w[i];
}

// ---- kv 1x1 conv: mid_feat -> bf16 vols[head][y][x][z][32ch] -------------
__global__ __launch_bounds__(256) void kv_kernel(const float* __restrict__ x,
    const float* __restrict__ kvw, const float* __restrict__ kvb,
    uint* __restrict__ vols){
  int v = blockIdx.x*256 + threadIdx.x;
  int z = v >> 12, y = (v >> 6) & 63, xx = v & 63;
  size_t widx = ((size_t)(y*WW + xx)*DD + z) * 16;
  float xr[CC];
  #pragma unroll
  for (int ci=0; ci<CC; ci++) xr[ci] = x[ci*VV + v];
  #pragma unroll 1
  for (int m=0; m<NHEADS; m++){
    float a[32];
    #pragma unroll 1
    for (int g=0; g<8; g++){
      int ch0 = m*32 + g*4;
      float a0=kvb[ch0], a1=kvb[ch0+1], a2=kvb[ch0+2], a3=kvb[ch0+3];
      #pragma unroll
      for (int ci=0; ci<CC; ci++){
        float xv = xr[ci];
        a0 += kvw[(ch0  )*CC+ci]*xv;
        a1 += kvw[(ch0+1)*CC+ci]*xv;
        a2 += kvw[(ch0+2)*CC+ci]*xv;
        a3 += kvw[(ch0+3)*CC+ci]*xv;
      }
      a[g*4+0]=a0; a[g*4+1]=a1; a[g*4+2]=a2; a[g*4+3]=a3;
    }
    uint4* dst = reinterpret_cast<uint4*>(vols + (size_t)m*VV*16 + widx);
    #pragma unroll
    for (int j=0; j<4; j++){
      uint4 p;
      p.x = packbf2(a[j*8+0], a[j*8+1]);
      p.y = packbf2(a[j*8+2], a[j*8+3]);
      p.z = packbf2(a[j*8+4], a[j*8+5]);
      p.w = packbf2(a[j*8+6], a[j*8+7]);
      dst[j] = p;
    }
  }
}

// ---- q 1x1 conv (scaled by HD^-0.5) -> qbuf[co][v] -----------------------
__global__ __launch_bounds__(256) void q_kernel(const float* __restrict__ x,
    const float* __restrict__ qw, const float* __restrict__ qb,
    float* __restrict__ qbuf){
  int v = blockIdx.x*256 + threadIdx.x;
  float xr[CC];
  #pragma unroll
  for (int ci=0; ci<CC; ci++) xr[ci] = x[ci*VV + v];
  #pragma unroll 1
  for (int g=0; g<16; g++){
    int co0 = g*4;
    float a0=qb[co0], a1=qb[co0+1], a2=qb[co0+2], a3=qb[co0+3];
    #pragma unroll
    for (int ci=0; ci<CC; ci++){
      float xv = xr[ci];
      a0 += qw[(co0  )*CC+ci]*xv;
      a1 += qw[(co0+1)*CC+ci]*xv;
      a2 += qw[(co0+2)*CC+ci]*xv;
      a3 += qw[(co0+3)*CC+ci]*xv;
    }
    qbuf[(co0  )*VV+v]=a0*0.25f;
    qbuf[(co0+1)*VV+v]=a1*0.25f;
    qbuf[(co0+2)*VV+v]=a2*0.25f;
    qbuf[(co0+3)*VV+v]=a3*0.25f;
  }
}

// ---- 3x3x3 conv via implicit-GEMM MFMA -----------------------------------
// Block: 8x8x1 voxel tile, MG waves (MG = CO/16). Wave g: co 16g..16g+15,
// all 64 voxels (4 n-tiles). Halo 3z x 10y x 10x x 64ci bf16 in LDS
// (row stride 72 -> 16B aligned, min-conflict), staged ONCE -> no barriers
// in the 54-step K-loop. ACT 0: +bias,gelu(exact). ACT 1: tanh.
template<int CO, int ACT>
__global__ __launch_bounds__((CO/16)*64) void conv3_mfma(
    const float* __restrict__ x, const uint* __restrict__ wA,
    const float* __restrict__ bias, float* __restrict__ out)
{
  constexpr int MG = CO/16;
  constexpr int NT = MG*64;
  __shared__ ushort xh[300*72];   // 43.2 KB
  int tid = threadIdx.x;
  int lane = tid & 63;
  int g = __builtin_amdgcn_readfirstlane(tid >> 6);
  int q = lane >> 4, n = lane & 15;
  int bid = blockIdx.x;
  // XCD-slab swizzle: XCD i (round-robin bid%8) works z in {2i, 2i+1}
  int xcd = bid & 7, islot = bid >> 3;
  int z  = xcd*2 + (islot >> 6);
  int rem = islot & 63;
  int by = (rem >> 3) << 3, bx = (rem & 7) << 3;

  // ---- stage halo (fp32 global -> bf16 LDS), zero-pad OOB ----
  for (int it = tid; it < 4800; it += NT){
    int ci4 = it / 300;          // 0..15 (4 ci each)
    int pos = it - ci4*300;
    int dz = pos/100; int r = pos - dz*100; int dy = r/10; int dxx = r - dy*10;
    int gz = z + dz - 1, gy = by + dy - 1, gx = bx + dxx - 1;
    float v0=0.f, v1=0.f, v2=0.f, v3=0.f;
    if (gz>=0 && gz<DD && gy>=0 && gy<HH && gx>=0 && gx<WW){
      size_t base = (size_t)(ci4*4)*VV + (size_t)((gz*HH+gy)*WW + gx);
      v0 = x[base]; v1 = x[base+VV]; v2 = x[base+2*(size_t)VV]; v3 = x[base+3*(size_t)VV];
    }
    uint2 pk; pk.x = packbf2(v0,v1); pk.y = packbf2(v2,v3);
    *reinterpret_cast<uint2*>(&xh[pos*72 + ci4*4]) = pk;
  }
  __syncthreads();

  // per-lane LDS byte offsets for the 4 n-tiles
  int lo[4];
  #pragma unroll
  for (int t=0;t<4;t++)
    lo[t] = ((2*t + (n>>3))*10 + (n&7))*144 + q*16;

  f32x4 acc[4];
  #pragma unroll
  for (int t=0;t<4;t++){ acc[t].x=0.f; acc[t].y=0.f; acc[t].z=0.f; acc[t].w=0.f; }

  const char* ldsb = reinterpret_cast<const char*>(xh);
  const char* wac  = reinterpret_cast<const char*>(wA);

  #pragma unroll 2
  for (int s=0; s<54; s++){
    int tap = s>>1, h = s&1;
    int dz = tap/9; int r9 = tap - dz*9; int dy = r9/3; int dxx = r9 - dy*3;
    int stepOff = (dz*100 + dy*10 + dxx)*144 + h*64;
    bf16x8 af = *reinterpret_cast<const bf16x8*>(wac + (size_t)(s*MG+g)*1024 + lane*16);
    #pragma unroll
    for (int t=0;t<4;t++){
      bf16x8 bf = *reinterpret_cast<const bf16x8*>(ldsb + (lo[t] + stepOff));
      acc[t] = __builtin_amdgcn_mfma_f32_16x16x32_bf16(af, bf, acc[t], 0, 0, 0);
    }
  }

  // ---- epilogue: C/D layout col=lane&15 (voxel), row=q*4+r (co) ----
  #pragma unroll
  for (int t=0;t<4;t++){
    int vy = by + 2*t + (n>>3), vx = bx + (n&7);
    int gv = (z*HH + vy)*WW + vx;
    #pragma unroll
    for (int r=0;r<4;r++){
      int co = g*16 + q*4 + r;
      float v = acc[t][r];
      if (ACT == 0){
        v += bias[co];
        v = 0.5f*v*(1.f + erff(v*0.70710678118654752f));
      } else {
        v = tanhf(v);
      }
      out[co*VV + gv] = v;
    }
  }
}

// ---- sampling geometry (replicates the reference's channel->axis swap) ---
struct Geom { int x0,x1,y0,y1,z0,z1; float wx,wy,wz; };
__device__ __forceinline__ Geom make_geom(float zb, float yb, float xb,
                                          float o0, float o1, float o2){
  float g0 = clampf(zb + o0*(1.f/16.f), -1.f, 1.f);
  float g1 = clampf(yb + o1*(1.f/64.f), -1.f, 1.f);
  float g2 = clampf(xb + o2*(1.f/64.f), -1.f, 1.f);
  float ix = (g0+1.f)*0.5f*63.f;
  float iy = (g1+1.f)*0.5f*63.f;
  float iz = (g2+1.f)*0.5f*15.f;
  float fx=floorf(ix), fy=floorf(iy), fz=floorf(iz);
  Geom g;
  g.wx = ix-fx; g.wy = iy-fy; g.wz = iz-fz;
  g.x0 = imin(imax((int)fx,0), WW-1); g.x1 = imin(g.x0+1, WW-1);
  g.y0 = imin(imax((int)fy,0), HH-1); g.y1 = imin(g.y0+1, HH-1);
  g.z0 = imin(imax((int)fz,0), DD-1); g.z1 = imin(g.z0+1, DD-1);
  return g;
}

// ---- sample + attention (online softmax, single pass) + out conv + BN ----
__global__ __launch_bounds__(256) void sample_attn_kernel(
    const float* __restrict__ qbuf, const float* __restrict__ offbuf,
    const uint* __restrict__ vols, const float* __restrict__ wout,
    const float* __restrict__ outb, const float* __restrict__ bng,
    const float* __restrict__ bnb, const float* __restrict__ bnm,
    const float* __restrict__ bnv, float* __restrict__ dout, int choff)
{
  __shared__ float fs[64*65];
  int t = threadIdx.x;
  int lv = t & 63;
  int m = __builtin_amdgcn_readfirstlane(t >> 6);
  int bid = blockIdx.x;
  int r = ((bid & 7) << 7) | (bid >> 3);      // XCD-slab swizzle
  int v = r*64 + lv;
  int z = v >> 12, y = (v >> 6) & 63, x = v & 63;
  float zb = -1.f + (float)z*(2.f/15.f);
  float yb = -1.f + (float)y*(2.f/63.f);
  float xb = -1.f + (float)x*(2.f/63.f);
  float q[HDIM];
  #pragma unroll
  for (int c=0;c<HDIM;c++) q[c] = qbuf[(m*HDIM+c)*VV + v];
  const uint* vol = vols + (size_t)m*VV*16;
  float mrun = -1e30f, lrun = 0.f;
  float fused[HDIM];
  #pragma unroll
  for (int c=0;c<HDIM;c++) fused[c]=0.f;
  #pragma unroll 1
  for (int s=0;s<NSAMP;s++){
    float o0 = offbuf[(m*24 + s*3 + 0)*VV + v];
    float o1 = offbuf[(m*24 + s*3 + 1)*VV + v];
    float o2 = offbuf[(m*24 + s*3 + 2)*VV + v];
    Geom g = make_geom(zb,yb,xb,o0,o1,o2);
    float lg = 0.f;
    float val[HDIM];
    #pragma unroll
    for (int c=0;c<HDIM;c++) val[c]=0.f;
    #pragma unroll
    for (int ky=0;ky<2;ky++)
    #pragma unroll
    for (int kx=0;kx<2;kx++){
      int cy = ky? g.y1:g.y0, cx = kx? g.x1:g.x0;
      float wyx = (ky? g.wy : 1.f-g.wy)*(kx? g.wx : 1.f-g.wx);
      size_t base = (size_t)(cy*WW + cx)*DD;
      #pragma unroll
      for (int kz=0;kz<2;kz++){
        int cz = kz? g.z1:g.z0;
        float cw = wyx * (kz? g.wz : 1.f-g.wz);
        const uint4* cp = reinterpret_cast<const uint4*>(vol + (base + cz)*16);
        uint4 k0 = cp[0], k1 = cp[1];
        uint4 v0 = cp[2], v1 = cp[3];
        lg += cw*(dot8(k0, q) + dot8(k1, q+8));
        acc8(v0, cw, val);
        acc8(v1, cw, val+8);
      }
    }
    float mnew = fmaxf(mrun, lg);
    float sc = expf(mrun - mnew);
    float e  = expf(lg - mnew);
    lrun = lrun*sc + e;
    #pragma unroll
    for (int c=0;c<HDIM;c++) fused[c] = fused[c]*sc + e*val[c];
    mrun = mnew;
  }
  float isum = 1.f/lrun;
  #pragma unroll
  for (int c=0;c<HDIM;c++) fs[lv*65 + m*HDIM + c] = fused[c]*isum;
  __syncthreads();
  float acc[16];
  #pragma unroll
  for (int k=0;k<16;k++) acc[k]=0.f;
  #pragma unroll 1
  for (int ci=0; ci<CC; ci++){
    float xv = fs[lv*65 + ci];
    const float* wp = wout + ci*CC + m*16;
    #pragma unroll
    for (int k=0;k<16;k++) acc[k] += wp[k]*xv;
  }
  #pragma unroll
  for (int k=0;k<16;k++){
    int co = m*16 + k;
    float vvv = acc[k] + outb[co];
    vvv = (vvv - bnm[co]) * rsqrtf(bnv[co] + 1e-5f) * bng[co] + bnb[co];
    vvv = fmaxf(vvv, 0.f);
    dout[(size_t)(choff+co)*VV + v] = vvv;
  }
}

extern "C" void kernel_launch(void* const* d_in, const int* in_sizes, int n_in,
                              void* d_out, int out_size, void* d_ws, size_t ws_size,
                              hipStream_t stream){
  (void)in_sizes; (void)n_in; (void)out_size; (void)ws_size;
  const float* mid  = (const float*)d_in[0];
  const float* occ  = (const float*)d_in[1];
  const float* prev = (const float*)d_in[2];
  const float* off1w= (const float*)d_in[3];
  const float* off1b= (const float*)d_in[4];
  const float* off2w= (const float*)d_in[5];
  const float* kvw  = (const float*)d_in[6];
  const float* kvb  = (const float*)d_in[7];
  const float* qw   = (const float*)d_in[8];
  const float* qb   = (const float*)d_in[9];
  const float* outw = (const float*)d_in[10];
  const float* outb = (const float*)d_in[11];
  const float* bng  = (const float*)d_in[12];
  const float* bnb  = (const float*)d_in[13];
  const float* bnm  = (const float*)d_in[14];
  const float* bnv  = (const float*)d_in[15];
  float* out = (float*)d_out;
  float* ws  = (float*)d_ws;

  uint*  vols   = (uint*)ws;                       // 4*V*16 uints
  float* qbuf   = ws     + (size_t)4*VV*16;        // 64*V floats
  float* o1buf  = qbuf   + (size_t)CC*VV;          // 64*V floats
  float* offbuf = o1buf  + (size_t)CC*VV;          // 96*V floats
  uint*  wA1    = (uint*)(offbuf + (size_t)96*VV); // 55296 uints
  uint*  wA2    = wA1 + 55296;                     // 82944 uints
  float* wpko   = (float*)(wA2 + 82944);           // 4096 floats

  repack_wmfma<<<(55296+255)/256, 256, 0, stream>>>(off1w, wA1, 4);
  repack_wmfma<<<(82944+255)/256, 256, 0, stream>>>(off2w, wA2, 6);
  repack_w1<<<16, 256, 0, stream>>>(outw, wpko);
  kv_kernel<<<VV/256, 256, 0, stream>>>(mid, kvw, kvb, vols);
  hipMemcpyAsync(out, mid, (size_t)CC*VV*sizeof(float), hipMemcpyDeviceToDevice, stream);

  const float* currs[2] = {occ, prev};
  for (int call=0; call<2; call++){
    const float* cur = currs[call];
    q_kernel<<<VV/256, 256, 0, stream>>>(cur, qw, qb, qbuf);
    conv3_mfma<64,0><<<1024, 256, 0, stream>>>(cur, wA1, off1b, o1buf);
    conv3_mfma<96,1><<<1024, 384, 0, stream>>>(o1buf, wA2, off1b, offbuf);
    sample_attn_kernel<<<VV/64, 256, 0, stream>>>(qbuf, offbuf, vols, wpko,
        outb, bng, bnb, bnm, bnv, out, 64 + call*64);
  }
}

// Round 5
// 537.991 us; speedup vs baseline: 6.1628x; 1.2239x over previous
//
#include <hip/hip_runtime.h>
#include <math.h>

#define DD 16
#define HH 64
#define WW 64
#define VV (DD*HH*WW)      // 65536
#define CC 64
#define NHEADS 4
#define NSAMP 8
#define HDIM 16

typedef unsigned int uint;
typedef unsigned short ushort;
typedef __attribute__((ext_vector_type(8))) short bf16x8;
typedef __attribute__((ext_vector_type(4))) float f32x4;

__device__ __forceinline__ float clampf(float v, float lo, float hi){ return fminf(fmaxf(v, lo), hi); }
__device__ __forceinline__ int imin(int a, int b){ return a < b ? a : b; }
__device__ __forceinline__ int imax(int a, int b){ return a > b ? a : b; }

// bf16 helpers (RNE)
__device__ __forceinline__ ushort f2bf(float f){
  uint u = __float_as_uint(f);
  uint r = (u + 0x7fffu + ((u>>16)&1u)) >> 16;
  return (ushort)r;
}
__device__ __forceinline__ uint packbf2(float a, float b){
  return (uint)f2bf(a) | ((uint)f2bf(b) << 16);
}
__device__ __forceinline__ float bflo(uint u){ return __uint_as_float(u << 16); }
__device__ __forceinline__ float bfhi(uint u){ return __uint_as_float(u & 0xffff0000u); }

__device__ __forceinline__ float dot8(uint4 k, const float* q){
  return q[0]*bflo(k.x)+q[1]*bfhi(k.x)+q[2]*bflo(k.y)+q[3]*bfhi(k.y)
       + q[4]*bflo(k.z)+q[5]*bfhi(k.z)+q[6]*bflo(k.w)+q[7]*bfhi(k.w);
}
__device__ __forceinline__ void acc8(uint4 u, float cw, float* val){
  val[0]+=cw*bflo(u.x); val[1]+=cw*bfhi(u.x);
  val[2]+=cw*bflo(u.y); val[3]+=cw*bfhi(u.y);
  val[4]+=cw*bflo(u.z); val[5]+=cw*bfhi(u.z);
  val[6]+=cw*bflo(u.w); val[7]+=cw*bfhi(u.w);
}

// ---- weight repacks ------------------------------------------------------
// 3x3x3 conv weights -> bf16 pairs in exact MFMA A-fragment order.
// lane = q*16+m holds A[co=g*16+m][k = q*8+j], ci = h*32 + q*8 + j.
__global__ void repack_wmfma(const float* __restrict__ w, uint* __restrict__ o, int MG){
  int U = blockIdx.x*256 + threadIdx.x;
  int total = 54*MG*256;
  if (U >= total) return;
  int j2 = U & 3;
  int m  = (U>>2) & 15;
  int q  = (U>>6) & 3;
  int rest = U >> 8;          // s*MG + g
  int g = rest % MG;
  int s = rest / MG;
  int tap = s >> 1, h = s & 1;
  int co = g*16 + m;
  int ci = h*32 + q*8 + j2*2;
  int base = co*1728 + ci*27 + tap;
  o[U] = packbf2(w[base], w[base + 27]);
}
// 1x1 conv weights [co][64ci] -> bf16 A-fragments: frag = ks*MT+mt,
// lane = q*16+m holds A[co=mt*16+m][ci = ks*32 + q*8 + j]
__global__ void repack_w1mfma(const float* __restrict__ w, uint* __restrict__ o, int MT){
  int U = blockIdx.x*256 + threadIdx.x;
  int total = 2*MT*256;
  if (U >= total) return;
  int j2 = U & 3;
  int lane = (U>>2) & 63;
  int frag = U >> 8;
  int mt = frag % MT;
  int ks = frag / MT;
  int q = lane >> 4, m = lane & 15;
  int co = mt*16 + m;
  int ci = ks*32 + q*8 + j2*2;
  o[U] = packbf2(w[co*CC + ci], w[co*CC + ci + 1]);
}
// out_w[co][ci] -> o[ci*64+co]
__global__ void repack_w1(const float* __restrict__ w, float* __restrict__ o){
  int i = blockIdx.x*256 + threadIdx.x; // 4096
  int co = i >> 6, ci = i & 63;
  o[ci*64 + co] = w[i];
}

// ---- 1x1 conv via MFMA ---------------------------------------------------
// Block: 64 voxels, 256 threads (4 waves). X tile staged [vox][ci] bf16,
// row stride 144 B. Wave g handles m-tiles g*MW..g*MW+MW-1, 4 n-tiles.
// EPI 0: +bias, pack bf16 -> vols[head][y][x][z][32ch] (kv, CO=128)
// EPI 1: (acc+bias)*0.25 -> fp32 out[co][v]            (q,  CO=64)
template<int CO, int EPI>
__global__ __launch_bounds__(256) void conv1_mfma(
    const float* __restrict__ x, const uint* __restrict__ wA,
    const float* __restrict__ bias, void* __restrict__ outp)
{
  constexpr int MT = CO/16;
  constexpr int MW = MT/4;
  __shared__ ushort xt[64*72];    // 9216 B
  int tid = threadIdx.x;
  int lane = tid & 63;
  int g = __builtin_amdgcn_readfirstlane(tid >> 6);
  int q = lane >> 4, n = lane & 15;
  int v0 = blockIdx.x * 64;
  // stage 64 vox x 64 ci (fp32 global, coalesced over vox -> bf16 LDS)
  for (int it = tid; it < 64*32; it += 256){
    int vox = it & 63; int cp = it >> 6;    // ci pair
    float a = x[(size_t)(2*cp)*VV + v0 + vox];
    float b = x[(size_t)(2*cp+1)*VV + v0 + vox];
    *reinterpret_cast<uint*>(&xt[vox*72 + 2*cp]) = packbf2(a,b);
  }
  __syncthreads();
  f32x4 acc[MW][4];
  #pragma unroll
  for (int mw=0;mw<MW;mw++)
    #pragma unroll
    for (int nt=0;nt<4;nt++){ acc[mw][nt].x=0.f; acc[mw][nt].y=0.f; acc[mw][nt].z=0.f; acc[mw][nt].w=0.f; }
  const char* ldsb = reinterpret_cast<const char*>(xt);
  const char* wac  = reinterpret_cast<const char*>(wA);
  #pragma unroll
  for (int ks=0; ks<2; ks++){
    bf16x8 bfr[4];
    #pragma unroll
    for (int nt=0; nt<4; nt++)
      bfr[nt] = *reinterpret_cast<const bf16x8*>(ldsb + ((nt*16+n)*144 + q*16 + ks*64));
    #pragma unroll
    for (int mw=0; mw<MW; mw++){
      int mt = g*MW + mw;
      bf16x8 af = *reinterpret_cast<const bf16x8*>(wac + (size_t)((ks*MT + mt)*64 + lane)*16);
      #pragma unroll
      for (int nt=0; nt<4; nt++)
        acc[mw][nt] = __builtin_amdgcn_mfma_f32_16x16x32_bf16(af, bfr[nt], acc[mw][nt], 0, 0, 0);
    }
  }
  // epilogue: C/D col = n (voxel), row = q*4+r (co within m-tile)
  #pragma unroll
  for (int mw=0; mw<MW; mw++){
    int mt = g*MW + mw;
    int cob = mt*16 + q*4;
    #pragma unroll
    for (int nt=0; nt<4; nt++){
      int v = v0 + nt*16 + n;
      float r0 = acc[mw][nt].x + bias[cob+0];
      float r1 = acc[mw][nt].y + bias[cob+1];
      float r2 = acc[mw][nt].z + bias[cob+2];
      float r3 = acc[mw][nt].w + bias[cob+3];
      if (EPI == 0){
        int z = v >> 12, y = (v >> 6) & 63, xx = v & 63;
        int head = cob >> 5;
        uint* vols = (uint*)outp;
        uint2 pk; pk.x = packbf2(r0,r1); pk.y = packbf2(r2,r3);
        *reinterpret_cast<uint2*>(vols + ((size_t)head*VV + (size_t)(y*WW+xx)*DD + z)*16 + ((cob&31)>>1)) = pk;
      } else {
        float* ob = (float*)outp;
        ob[(size_t)(cob+0)*VV + v] = r0*0.25f;
        ob[(size_t)(cob+1)*VV + v] = r1*0.25f;
        ob[(size_t)(cob+2)*VV + v] = r2*0.25f;
        ob[(size_t)(cob+3)*VV + v] = r3*0.25f;
      }
    }
  }
}

// ---- 3x3x3 conv via implicit-GEMM MFMA -----------------------------------
template<int CO, int ACT>
__global__ __launch_bounds__((CO/16)*64) void conv3_mfma(
    const float* __restrict__ x, const uint* __restrict__ wA,
    const float* __restrict__ bias, float* __restrict__ out)
{
  constexpr int MG = CO/16;
  constexpr int NT = MG*64;
  __shared__ ushort xh[300*72];   // 43.2 KB
  int tid = threadIdx.x;
  int lane = tid & 63;
  int g = __builtin_amdgcn_readfirstlane(tid >> 6);
  int q = lane >> 4, n = lane & 15;
  int bid = blockIdx.x;
  int xcd = bid & 7, islot = bid >> 3;
  int z  = xcd*2 + (islot >> 6);
  int rem = islot & 63;
  int by = (rem >> 3) << 3, bx = (rem & 7) << 3;

  for (int it = tid; it < 4800; it += NT){
    int ci4 = it / 300;
    int pos = it - ci4*300;
    int dz = pos/100; int r = pos - dz*100; int dy = r/10; int dxx = r - dy*10;
    int gz = z + dz - 1, gy = by + dy - 1, gx = bx + dxx - 1;
    float v0=0.f, v1=0.f, v2=0.f, v3=0.f;
    if (gz>=0 && gz<DD && gy>=0 && gy<HH && gx>=0 && gx<WW){
      size_t base = (size_t)(ci4*4)*VV + (size_t)((gz*HH+gy)*WW + gx);
      v0 = x[base]; v1 = x[base+VV]; v2 = x[base+2*(size_t)VV]; v3 = x[base+3*(size_t)VV];
    }
    uint2 pk; pk.x = packbf2(v0,v1); pk.y = packbf2(v2,v3);
    *reinterpret_cast<uint2*>(&xh[pos*72 + ci4*4]) = pk;
  }
  __syncthreads();

  int lo[4];
  #pragma unroll
  for (int t=0;t<4;t++)
    lo[t] = ((2*t + (n>>3))*10 + (n&7))*144 + q*16;

  f32x4 acc[4];
  #pragma unroll
  for (int t=0;t<4;t++){ acc[t].x=0.f; acc[t].y=0.f; acc[t].z=0.f; acc[t].w=0.f; }

  const char* ldsb = reinterpret_cast<const char*>(xh);
  const char* wac  = reinterpret_cast<const char*>(wA);

  #pragma unroll 2
  for (int s=0; s<54; s++){
    int tap = s>>1, h = s&1;
    int dz = tap/9; int r9 = tap - dz*9; int dy = r9/3; int dxx = r9 - dy*3;
    int stepOff = (dz*100 + dy*10 + dxx)*144 + h*64;
    bf16x8 af = *reinterpret_cast<const bf16x8*>(wac + (size_t)(s*MG+g)*1024 + lane*16);
    #pragma unroll
    for (int t=0;t<4;t++){
      bf16x8 bf = *reinterpret_cast<const bf16x8*>(ldsb + (lo[t] + stepOff));
      acc[t] = __builtin_amdgcn_mfma_f32_16x16x32_bf16(af, bf, acc[t], 0, 0, 0);
    }
  }

  #pragma unroll
  for (int t=0;t<4;t++){
    int vy = by + 2*t + (n>>3), vx = bx + (n&7);
    int gv = (z*HH + vy)*WW + vx;
    #pragma unroll
    for (int r=0;r<4;r++){
      int co = g*16 + q*4 + r;
      float v = acc[t][r];
      if (ACT == 0){
        v += bias[co];
        v = 0.5f*v*(1.f + erff(v*0.70710678118654752f));
      } else {
        v = tanhf(v);
      }
      out[co*VV + gv] = v;
    }
  }
}

// ---- sampling geometry (replicates the reference's channel->axis swap) ---
struct Geom { int x0,x1,y0,y1,z0,z1; float wx,wy,wz; };
__device__ __forceinline__ Geom make_geom(float zb, float yb, float xb,
                                          float o0, float o1, float o2){
  float g0 = clampf(zb + o0*(1.f/16.f), -1.f, 1.f);
  float g1 = clampf(yb + o1*(1.f/64.f), -1.f, 1.f);
  float g2 = clampf(xb + o2*(1.f/64.f), -1.f, 1.f);
  float ix = (g0+1.f)*0.5f*63.f;
  float iy = (g1+1.f)*0.5f*63.f;
  float iz = (g2+1.f)*0.5f*15.f;
  float fx=floorf(ix), fy=floorf(iy), fz=floorf(iz);
  Geom g;
  g.wx = ix-fx; g.wy = iy-fy; g.wz = iz-fz;
  g.x0 = imin(imax((int)fx,0), WW-1); g.x1 = imin(g.x0+1, WW-1);
  g.y0 = imin(imax((int)fy,0), HH-1); g.y1 = imin(g.y0+1, HH-1);
  g.z0 = imin(imax((int)fz,0), DD-1); g.z1 = imin(g.z0+1, DD-1);
  return g;
}

// ---- sample + attention (online softmax, single pass) + out conv + BN ----
__global__ __launch_bounds__(256) void sample_attn_kernel(
    const float* __restrict__ qbuf, const float* __restrict__ offbuf,
    const uint* __restrict__ vols, const float* __restrict__ wout,
    const float* __restrict__ outb, const float* __restrict__ bng,
    const float* __restrict__ bnb, const float* __restrict__ bnm,
    const float* __restrict__ bnv, float* __restrict__ dout, int choff)
{
  __shared__ float fs[64*65];
  int t = threadIdx.x;
  int lv = t & 63;
  int m = __builtin_amdgcn_readfirstlane(t >> 6);
  int bid = blockIdx.x;
  int r = ((bid & 7) << 7) | (bid >> 3);      // XCD-slab swizzle
  int v = r*64 + lv;
  int z = v >> 12, y = (v >> 6) & 63, x = v & 63;
  float zb = -1.f + (float)z*(2.f/15.f);
  float yb = -1.f + (float)y*(2.f/63.f);
  float xb = -1.f + (float)x*(2.f/63.f);
  float q[HDIM];
  #pragma unroll
  for (int c=0;c<HDIM;c++) q[c] = qbuf[(m*HDIM+c)*VV + v];
  const uint* vol = vols + (size_t)m*VV*16;
  float mrun = -1e30f, lrun = 0.f;
  float fused[HDIM];
  #pragma unroll
  for (int c=0;c<HDIM;c++) fused[c]=0.f;
  #pragma unroll 1
  for (int s=0;s<NSAMP;s++){
    float o0 = offbuf[(m*24 + s*3 + 0)*VV + v];
    float o1 = offbuf[(m*24 + s*3 + 1)*VV + v];
    float o2 = offbuf[(m*24 + s*3 + 2)*VV + v];
    Geom g = make_geom(zb,yb,xb,o0,o1,o2);
    float lg = 0.f;
    float val[HDIM];
    #pragma unroll
    for (int c=0;c<HDIM;c++) val[c]=0.f;
    #pragma unroll
    for (int ky=0;ky<2;ky++)
    #pragma unroll
    for (int kx=0;kx<2;kx++){
      int cy = ky? g.y1:g.y0, cx = kx? g.x1:g.x0;
      float wyx = (ky? g.wy : 1.f-g.wy)*(kx? g.wx : 1.f-g.wx);
      size_t base = (size_t)(cy*WW + cx)*DD;
      #pragma unroll
      for (int kz=0;kz<2;kz++){
        int cz = kz? g.z1:g.z0;
        float cw = wyx * (kz? g.wz : 1.f-g.wz);
        const uint4* cp = reinterpret_cast<const uint4*>(vol + (base + cz)*16);
        uint4 k0 = cp[0], k1 = cp[1];
        uint4 v0 = cp[2], v1 = cp[3];
        lg += cw*(dot8(k0, q) + dot8(k1, q+8));
        acc8(v0, cw, val);
        acc8(v1, cw, val+8);
      }
    }
    float mnew = fmaxf(mrun, lg);
    float sc = expf(mrun - mnew);
    float e  = expf(lg - mnew);
    lrun = lrun*sc + e;
    #pragma unroll
    for (int c=0;c<HDIM;c++) fused[c] = fused[c]*sc + e*val[c];
    mrun = mnew;
  }
  float isum = 1.f/lrun;
  #pragma unroll
  for (int c=0;c<HDIM;c++) fs[lv*65 + m*HDIM + c] = fused[c]*isum;
  __syncthreads();
  float acc[16];
  #pragma unroll
  for (int k=0;k<16;k++) acc[k]=0.f;
  #pragma unroll 1
  for (int ci=0; ci<CC; ci++){
    float xv = fs[lv*65 + ci];
    const float* wp = wout + ci*CC + m*16;
    #pragma unroll
    for (int k=0;k<16;k++) acc[k] += wp[k]*xv;
  }
  #pragma unroll
  for (int k=0;k<16;k++){
    int co = m*16 + k;
    float vvv = acc[k] + outb[co];
    vvv = (vvv - bnm[co]) * rsqrtf(bnv[co] + 1e-5f) * bng[co] + bnb[co];
    vvv = fmaxf(vvv, 0.f);
    dout[(size_t)(choff+co)*VV + v] = vvv;
  }
}

extern "C" void kernel_launch(void* const* d_in, const int* in_sizes, int n_in,
                              void* d_out, int out_size, void* d_ws, size_t ws_size,
                              hipStream_t stream){
  (void)in_sizes; (void)n_in; (void)out_size; (void)ws_size;
  const float* mid  = (const float*)d_in[0];
  const float* occ  = (const float*)d_in[1];
  const float* prev = (const float*)d_in[2];
  const float* off1w= (const float*)d_in[3];
  const float* off1b= (const float*)d_in[4];
  const float* off2w= (const float*)d_in[5];
  const float* kvw  = (const float*)d_in[6];
  const float* kvb  = (const float*)d_in[7];
  const float* qw   = (const float*)d_in[8];
  const float* qb   = (const float*)d_in[9];
  const float* outw = (const float*)d_in[10];
  const float* outb = (const float*)d_in[11];
  const float* bng  = (const float*)d_in[12];
  const float* bnb  = (const float*)d_in[13];
  const float* bnm  = (const float*)d_in[14];
  const float* bnv  = (const float*)d_in[15];
  float* out = (float*)d_out;
  float* ws  = (float*)d_ws;

  uint*  vols   = (uint*)ws;                       // 4*V*16 uints
  float* qbuf   = ws     + (size_t)4*VV*16;        // 64*V floats
  float* o1buf  = qbuf   + (size_t)CC*VV;          // 64*V floats
  float* offbuf = o1buf  + (size_t)CC*VV;          // 96*V floats
  uint*  wA1    = (uint*)(offbuf + (size_t)96*VV); // 55296 uints
  uint*  wA2    = wA1 + 55296;                     // 82944 uints
  float* wpko   = (float*)(wA2 + 82944);           // 4096 floats
  uint*  wkv    = (uint*)(wpko + 4096);            // 4096 uints
  uint*  wq     = wkv + 4096;                      // 2048 uints

  repack_wmfma<<<(55296+255)/256, 256, 0, stream>>>(off1w, wA1, 4);
  repack_wmfma<<<(82944+255)/256, 256, 0, stream>>>(off2w, wA2, 6);
  repack_w1<<<16, 256, 0, stream>>>(outw, wpko);
  repack_w1mfma<<<(4096+255)/256, 256, 0, stream>>>(kvw, wkv, 8);
  repack_w1mfma<<<(2048+255)/256, 256, 0, stream>>>(qw, wq, 4);
  conv1_mfma<128,0><<<VV/64, 256, 0, stream>>>(mid, wkv, kvb, (void*)vols);
  hipMemcpyAsync(out, mid, (size_t)CC*VV*sizeof(float), hipMemcpyDeviceToDevice, stream);

  const float* currs[2] = {occ, prev};
  for (int call=0; call<2; call++){
    const float* cur = currs[call];
    conv1_mfma<64,1><<<VV/64, 256, 0, stream>>>(cur, wq, qb, (void*)qbuf);
    conv3_mfma<64,0><<<1024, 256, 0, stream>>>(cur, wA1, off1b, o1buf);
    conv3_mfma<96,1><<<1024, 384, 0, stream>>>(o1buf, wA2, off1b, offbuf);
    sample_attn_kernel<<<VV/64, 256, 0, stream>>>(qbuf, offbuf, vols, wpko,
        outb, bng, bnb, bnm, bnv, out, 64 + call*64);
  }
}

// Round 6
// 508.514 us; speedup vs baseline: 6.5200x; 1.0580x over previous
//
#include <hip/hip_runtime.h>
#include <math.h>

#define DD 16
#define HH 64
#define WW 64
#define VV (DD*HH*WW)      // 65536
#define CC 64
#define NHEADS 4
#define NSAMP 8
#define HDIM 16

typedef unsigned int uint;
typedef unsigned short ushort;
typedef __attribute__((ext_vector_type(8))) short bf16x8;
typedef __attribute__((ext_vector_type(4))) float f32x4;

__device__ __forceinline__ float clampf(float v, float lo, float hi){ return fminf(fmaxf(v, lo), hi); }
__device__ __forceinline__ int imin(int a, int b){ return a < b ? a : b; }
__device__ __forceinline__ int imax(int a, int b){ return a > b ? a : b; }

// bf16 helpers (RNE)
__device__ __forceinline__ ushort f2bf(float f){
  uint u = __float_as_uint(f);
  uint r = (u + 0x7fffu + ((u>>16)&1u)) >> 16;
  return (ushort)r;
}
__device__ __forceinline__ uint packbf2(float a, float b){
  return (uint)f2bf(a) | ((uint)f2bf(b) << 16);
}
__device__ __forceinline__ float bflo(uint u){ return __uint_as_float(u << 16); }
__device__ __forceinline__ float bfhi(uint u){ return __uint_as_float(u & 0xffff0000u); }

__device__ __forceinline__ float dot8(uint4 k, const float* q){
  return q[0]*bflo(k.x)+q[1]*bfhi(k.x)+q[2]*bflo(k.y)+q[3]*bfhi(k.y)
       + q[4]*bflo(k.z)+q[5]*bfhi(k.z)+q[6]*bflo(k.w)+q[7]*bfhi(k.w);
}
__device__ __forceinline__ void acc8(uint4 u, float cw, float* val){
  val[0]+=cw*bflo(u.x); val[1]+=cw*bfhi(u.x);
  val[2]+=cw*bflo(u.y); val[3]+=cw*bfhi(u.y);
  val[4]+=cw*bflo(u.z); val[5]+=cw*bfhi(u.z);
  val[6]+=cw*bflo(u.w); val[7]+=cw*bfhi(u.w);
}

// ---- weight repacks ------------------------------------------------------
// 3x3x3 conv weights -> bf16 pairs in exact MFMA A-fragment order.
__global__ void repack_wmfma(const float* __restrict__ w, uint* __restrict__ o, int MG){
  int U = blockIdx.x*256 + threadIdx.x;
  int total = 54*MG*256;
  if (U >= total) return;
  int j2 = U & 3;
  int m  = (U>>2) & 15;
  int q  = (U>>6) & 3;
  int rest = U >> 8;          // s*MG + g
  int g = rest % MG;
  int s = rest / MG;
  int tap = s >> 1, h = s & 1;
  int co = g*16 + m;
  int ci = h*32 + q*8 + j2*2;
  int base = co*1728 + ci*27 + tap;
  o[U] = packbf2(w[base], w[base + 27]);
}
// 1x1 conv weights [co][64ci] -> bf16 A-fragments: frag = ks*MT+mt,
// lane = q*16+m holds A[co=mt*16+m][ci = ks*32 + q*8 + j]
__global__ void repack_w1mfma(const float* __restrict__ w, uint* __restrict__ o, int MT){
  int U = blockIdx.x*256 + threadIdx.x;
  int total = 2*MT*256;
  if (U >= total) return;
  int j2 = U & 3;
  int lane = (U>>2) & 63;
  int frag = U >> 8;
  int mt = frag % MT;
  int ks = frag / MT;
  int q = lane >> 4, m = lane & 15;
  int co = mt*16 + m;
  int ci = ks*32 + q*8 + j2*2;
  o[U] = packbf2(w[co*CC + ci], w[co*CC + ci + 1]);
}

// ---- 1x1 conv via MFMA ---------------------------------------------------
template<int CO, int EPI>
__global__ __launch_bounds__(256) void conv1_mfma(
    const float* __restrict__ x, const uint* __restrict__ wA,
    const float* __restrict__ bias, void* __restrict__ outp)
{
  constexpr int MT = CO/16;
  constexpr int MW = MT/4;
  __shared__ ushort xt[64*72];    // 9216 B
  int tid = threadIdx.x;
  int lane = tid & 63;
  int g = __builtin_amdgcn_readfirstlane(tid >> 6);
  int q = lane >> 4, n = lane & 15;
  int v0 = blockIdx.x * 64;
  for (int it = tid; it < 64*32; it += 256){
    int vox = it & 63; int cp = it >> 6;    // ci pair
    float a = x[(size_t)(2*cp)*VV + v0 + vox];
    float b = x[(size_t)(2*cp+1)*VV + v0 + vox];
    *reinterpret_cast<uint*>(&xt[vox*72 + 2*cp]) = packbf2(a,b);
  }
  __syncthreads();
  f32x4 acc[MW][4];
  #pragma unroll
  for (int mw=0;mw<MW;mw++)
    #pragma unroll
    for (int nt=0;nt<4;nt++){ acc[mw][nt].x=0.f; acc[mw][nt].y=0.f; acc[mw][nt].z=0.f; acc[mw][nt].w=0.f; }
  const char* ldsb = reinterpret_cast<const char*>(xt);
  const char* wac  = reinterpret_cast<const char*>(wA);
  #pragma unroll
  for (int ks=0; ks<2; ks++){
    bf16x8 bfr[4];
    #pragma unroll
    for (int nt=0; nt<4; nt++)
      bfr[nt] = *reinterpret_cast<const bf16x8*>(ldsb + ((nt*16+n)*144 + q*16 + ks*64));
    #pragma unroll
    for (int mw=0; mw<MW; mw++){
      int mt = g*MW + mw;
      bf16x8 af = *reinterpret_cast<const bf16x8*>(wac + (size_t)((ks*MT + mt)*64 + lane)*16);
      #pragma unroll
      for (int nt=0; nt<4; nt++)
        acc[mw][nt] = __builtin_amdgcn_mfma_f32_16x16x32_bf16(af, bfr[nt], acc[mw][nt], 0, 0, 0);
    }
  }
  #pragma unroll
  for (int mw=0; mw<MW; mw++){
    int mt = g*MW + mw;
    int cob = mt*16 + q*4;
    #pragma unroll
    for (int nt=0; nt<4; nt++){
      int v = v0 + nt*16 + n;
      float r0 = acc[mw][nt].x + bias[cob+0];
      float r1 = acc[mw][nt].y + bias[cob+1];
      float r2 = acc[mw][nt].z + bias[cob+2];
      float r3 = acc[mw][nt].w + bias[cob+3];
      if (EPI == 0){
        int z = v >> 12, y = (v >> 6) & 63, xx = v & 63;
        int head = cob >> 5;
        uint* vols = (uint*)outp;
        uint2 pk; pk.x = packbf2(r0,r1); pk.y = packbf2(r2,r3);
        *reinterpret_cast<uint2*>(vols + ((size_t)head*VV + (size_t)(y*WW+xx)*DD + z)*16 + ((cob&31)>>1)) = pk;
      } else {
        float* ob = (float*)outp;
        ob[(size_t)(cob+0)*VV + v] = r0*0.25f;
        ob[(size_t)(cob+1)*VV + v] = r1*0.25f;
        ob[(size_t)(cob+2)*VV + v] = r2*0.25f;
        ob[(size_t)(cob+3)*VV + v] = r3*0.25f;
      }
    }
  }
}

// ---- 3x3x3 conv via implicit-GEMM MFMA -----------------------------------
template<int CO, int ACT>
__global__ __launch_bounds__((CO/16)*64) void conv3_mfma(
    const float* __restrict__ x, const uint* __restrict__ wA,
    const float* __restrict__ bias, float* __restrict__ out)
{
  constexpr int MG = CO/16;
  constexpr int NT = MG*64;
  __shared__ ushort xh[300*72];   // 43.2 KB
  int tid = threadIdx.x;
  int lane = tid & 63;
  int g = __builtin_amdgcn_readfirstlane(tid >> 6);
  int q = lane >> 4, n = lane & 15;
  int bid = blockIdx.x;
  int xcd = bid & 7, islot = bid >> 3;
  int z  = xcd*2 + (islot >> 6);
  int rem = islot & 63;
  int by = (rem >> 3) << 3, bx = (rem & 7) << 3;

  for (int it = tid; it < 4800; it += NT){
    int ci4 = it / 300;
    int pos = it - ci4*300;
    int dz = pos/100; int r = pos - dz*100; int dy = r/10; int dxx = r - dy*10;
    int gz = z + dz - 1, gy = by + dy - 1, gx = bx + dxx - 1;
    float v0=0.f, v1=0.f, v2=0.f, v3=0.f;
    if (gz>=0 && gz<DD && gy>=0 && gy<HH && gx>=0 && gx<WW){
      size_t base = (size_t)(ci4*4)*VV + (size_t)((gz*HH+gy)*WW + gx);
      v0 = x[base]; v1 = x[base+VV]; v2 = x[base+2*(size_t)VV]; v3 = x[base+3*(size_t)VV];
    }
    uint2 pk; pk.x = packbf2(v0,v1); pk.y = packbf2(v2,v3);
    *reinterpret_cast<uint2*>(&xh[pos*72 + ci4*4]) = pk;
  }
  __syncthreads();

  int lo[4];
  #pragma unroll
  for (int t=0;t<4;t++)
    lo[t] = ((2*t + (n>>3))*10 + (n&7))*144 + q*16;

  f32x4 acc[4];
  #pragma unroll
  for (int t=0;t<4;t++){ acc[t].x=0.f; acc[t].y=0.f; acc[t].z=0.f; acc[t].w=0.f; }

  const char* ldsb = reinterpret_cast<const char*>(xh);
  const char* wac  = reinterpret_cast<const char*>(wA);

  #pragma unroll 2
  for (int s=0; s<54; s++){
    int tap = s>>1, h = s&1;
    int dz = tap/9; int r9 = tap - dz*9; int dy = r9/3; int dxx = r9 - dy*3;
    int stepOff = (dz*100 + dy*10 + dxx)*144 + h*64;
    bf16x8 af = *reinterpret_cast<const bf16x8*>(wac + (size_t)(s*MG+g)*1024 + lane*16);
    #pragma unroll
    for (int t=0;t<4;t++){
      bf16x8 bf = *reinterpret_cast<const bf16x8*>(ldsb + (lo[t] + stepOff));
      acc[t] = __builtin_amdgcn_mfma_f32_16x16x32_bf16(af, bf, acc[t], 0, 0, 0);
    }
  }

  #pragma unroll
  for (int t=0;t<4;t++){
    int vy = by + 2*t + (n>>3), vx = bx + (n&7);
    int gv = (z*HH + vy)*WW + vx;
    #pragma unroll
    for (int r=0;r<4;r++){
      int co = g*16 + q*4 + r;
      float v = acc[t][r];
      if (ACT == 0){
        v += bias[co];
        v = 0.5f*v*(1.f + erff(v*0.70710678118654752f));
      } else {
        v = tanhf(v);
      }
      out[co*VV + gv] = v;
    }
  }
}

// ---- sampling geometry (replicates the reference's channel->axis swap) ---
struct Geom { int x0,x1,y0,y1,z0,z1; float wx,wy,wz; };
__device__ __forceinline__ Geom make_geom(float zb, float yb, float xb,
                                          float o0, float o1, float o2){
  float g0 = clampf(zb + o0*(1.f/16.f), -1.f, 1.f);
  float g1 = clampf(yb + o1*(1.f/64.f), -1.f, 1.f);
  float g2 = clampf(xb + o2*(1.f/64.f), -1.f, 1.f);
  float ix = (g0+1.f)*0.5f*63.f;
  float iy = (g1+1.f)*0.5f*63.f;
  float iz = (g2+1.f)*0.5f*15.f;
  float fx=floorf(ix), fy=floorf(iy), fz=floorf(iz);
  Geom g;
  g.wx = ix-fx; g.wy = iy-fy; g.wz = iz-fz;
  g.x0 = imin(imax((int)fx,0), WW-1); g.x1 = imin(g.x0+1, WW-1);
  g.y0 = imin(imax((int)fy,0), HH-1); g.y1 = imin(g.y0+1, HH-1);
  g.z0 = imin(imax((int)fz,0), DD-1); g.z1 = imin(g.z0+1, DD-1);
  return g;
}

// ---- sample + attention (online softmax) + MFMA out conv + BN + relu -----
// block: 64 voxels (one x-row) x 4 heads (one wave per head)
__global__ __launch_bounds__(256) void sample_attn_kernel(
    const float* __restrict__ qbuf, const float* __restrict__ offbuf,
    const uint* __restrict__ vols, const uint* __restrict__ woA,
    const float* __restrict__ outb, const float* __restrict__ bng,
    const float* __restrict__ bnb, const float* __restrict__ bnm,
    const float* __restrict__ bnv, float* __restrict__ dout, int choff)
{
  __shared__ ushort fsb[64*72];   // fused attn output, bf16 [vox][ci], 144B rows
  int t = threadIdx.x;
  int lv = t & 63;
  int m = __builtin_amdgcn_readfirstlane(t >> 6);
  int bid = blockIdx.x;
  int r = ((bid & 7) << 7) | (bid >> 3);      // XCD-slab swizzle
  int v0 = r*64;
  int v = v0 + lv;
  int z = v >> 12, y = (v >> 6) & 63, x = v & 63;
  float zb = -1.f + (float)z*(2.f/15.f);
  float yb = -1.f + (float)y*(2.f/63.f);
  float xb = -1.f + (float)x*(2.f/63.f);
  float q[HDIM];
  #pragma unroll
  for (int c=0;c<HDIM;c++) q[c] = qbuf[(m*HDIM+c)*VV + v];
  const uint* vol = vols + (size_t)m*VV*16;
  float mrun = -1e30f, lrun = 0.f;
  float fused[HDIM];
  #pragma unroll
  for (int c=0;c<HDIM;c++) fused[c]=0.f;
  #pragma unroll 2
  for (int s=0;s<NSAMP;s++){
    float o0 = offbuf[(m*24 + s*3 + 0)*VV + v];
    float o1 = offbuf[(m*24 + s*3 + 1)*VV + v];
    float o2 = offbuf[(m*24 + s*3 + 2)*VV + v];
    Geom g = make_geom(zb,yb,xb,o0,o1,o2);
    float lg = 0.f;
    float val[HDIM];
    #pragma unroll
    for (int c=0;c<HDIM;c++) val[c]=0.f;
    #pragma unroll
    for (int ky=0;ky<2;ky++)
    #pragma unroll
    for (int kx=0;kx<2;kx++){
      int cy = ky? g.y1:g.y0, cx = kx? g.x1:g.x0;
      float wyx = (ky? g.wy : 1.f-g.wy)*(kx? g.wx : 1.f-g.wx);
      size_t base = (size_t)(cy*WW + cx)*DD;
      #pragma unroll
      for (int kz=0;kz<2;kz++){
        int cz = kz? g.z1:g.z0;
        float cw = wyx * (kz? g.wz : 1.f-g.wz);
        const uint4* cp = reinterpret_cast<const uint4*>(vol + (base + cz)*16);
        uint4 k0 = cp[0], k1 = cp[1];
        uint4 vv0 = cp[2], vv1 = cp[3];
        lg += cw*(dot8(k0, q) + dot8(k1, q+8));
        acc8(vv0, cw, val);
        acc8(vv1, cw, val+8);
      }
    }
    float mnew = fmaxf(mrun, lg);
    float sc = expf(mrun - mnew);
    float e  = expf(lg - mnew);
    lrun = lrun*sc + e;
    #pragma unroll
    for (int c=0;c<HDIM;c++) fused[c] = fused[c]*sc + e*val[c];
    mrun = mnew;
  }
  float isum = 1.f/lrun;
  #pragma unroll
  for (int c2=0;c2<8;c2++)
    *reinterpret_cast<uint*>(&fsb[lv*72 + m*HDIM + 2*c2]) =
        packbf2(fused[2*c2]*isum, fused[2*c2+1]*isum);
  __syncthreads();

  // ---- out 1x1 conv via MFMA: wave m computes co-tile m (16 co) x 64 vox
  int lane = t & 63;
  int qq = lane >> 4, n = lane & 15;
  f32x4 acc[4];
  #pragma unroll
  for (int nt=0;nt<4;nt++){ acc[nt].x=0.f; acc[nt].y=0.f; acc[nt].z=0.f; acc[nt].w=0.f; }
  const char* ldsb = reinterpret_cast<const char*>(fsb);
  const char* wac  = reinterpret_cast<const char*>(woA);
  #pragma unroll
  for (int ks=0; ks<2; ks++){
    bf16x8 af = *reinterpret_cast<const bf16x8*>(wac + (size_t)((ks*4 + m)*64 + lane)*16);
    #pragma unroll
    for (int nt=0; nt<4; nt++){
      bf16x8 bf = *reinterpret_cast<const bf16x8*>(ldsb + ((nt*16+n)*144 + qq*16 + ks*64));
      acc[nt] = __builtin_amdgcn_mfma_f32_16x16x32_bf16(af, bf, acc[nt], 0, 0, 0);
    }
  }
  #pragma unroll
  for (int rr=0; rr<4; rr++){
    int co = m*16 + qq*4 + rr;
    float scl = rsqrtf(bnv[co] + 1e-5f) * bng[co];
    float add = bnb[co] - (bnm[co] - outb[co]) * scl;
    #pragma unroll
    for (int nt=0; nt<4; nt++){
      float vvv = fmaxf(acc[nt][rr]*scl*1.f + (outb[co]-outb[co]) + acc[nt][rr]*0.f + acc[nt][rr]*0.f, -1e30f); // placeholder avoided below
    }
  }
  // (compute epilogue cleanly)
  #pragma unroll
  for (int nt=0; nt<4; nt++){
    int vv = v0 + nt*16 + n;
    #pragma unroll
    for (int rr=0; rr<4; rr++){
      int co = m*16 + qq*4 + rr;
      float inv = rsqrtf(bnv[co] + 1e-5f) * bng[co];
      float val = (acc[nt][rr] + outb[co] - bnm[co]) * inv + bnb[co];
      val = fmaxf(val, 0.f);
      dout[(size_t)(choff+co)*VV + vv] = val;
    }
  }
}

extern "C" void kernel_launch(void* const* d_in, const int* in_sizes, int n_in,
                              void* d_out, int out_size, void* d_ws, size_t ws_size,
                              hipStream_t stream){
  (void)in_sizes; (void)n_in; (void)out_size; (void)ws_size;
  const float* mid  = (const float*)d_in[0];
  const float* occ  = (const float*)d_in[1];
  const float* prev = (const float*)d_in[2];
  const float* off1w= (const float*)d_in[3];
  const float* off1b= (const float*)d_in[4];
  const float* off2w= (const float*)d_in[5];
  const float* kvw  = (const float*)d_in[6];
  const float* kvb  = (const float*)d_in[7];
  const float* qw   = (const float*)d_in[8];
  const float* qb   = (const float*)d_in[9];
  const float* outw = (const float*)d_in[10];
  const float* outb = (const float*)d_in[11];
  const float* bng  = (const float*)d_in[12];
  const float* bnb  = (const float*)d_in[13];
  const float* bnm  = (const float*)d_in[14];
  const float* bnv  = (const float*)d_in[15];
  float* out = (float*)d_out;
  float* ws  = (float*)d_ws;

  uint*  vols   = (uint*)ws;                       // 4*V*16 uints
  float* qbuf   = ws     + (size_t)4*VV*16;        // 64*V floats
  float* o1buf  = qbuf   + (size_t)CC*VV;          // 64*V floats
  float* offbuf = o1buf  + (size_t)CC*VV;          // 96*V floats
  uint*  wA1    = (uint*)(offbuf + (size_t)96*VV); // 55296 uints
  uint*  wA2    = wA1 + 55296;                     // 82944 uints
  uint*  wo     = wA2 + 82944;                     // 2048 uints
  uint*  wkv    = wo  + 2048;                      // 4096 uints
  uint*  wq     = wkv + 4096;                      // 2048 uints

  repack_wmfma<<<(55296+255)/256, 256, 0, stream>>>(off1w, wA1, 4);
  repack_wmfma<<<(82944+255)/256, 256, 0, stream>>>(off2w, wA2, 6);
  repack_w1mfma<<<(2048+255)/256, 256, 0, stream>>>(outw, wo, 4);
  repack_w1mfma<<<(4096+255)/256, 256, 0, stream>>>(kvw, wkv, 8);
  repack_w1mfma<<<(2048+255)/256, 256, 0, stream>>>(qw, wq, 4);
  conv1_mfma<128,0><<<VV/64, 256, 0, stream>>>(mid, wkv, kvb, (void*)vols);
  hipMemcpyAsync(out, mid, (size_t)CC*VV*sizeof(float), hipMemcpyDeviceToDevice, stream);

  const float* currs[2] = {occ, prev};
  for (int call=0; call<2; call++){
    const float* cur = currs[call];
    conv1_mfma<64,1><<<VV/64, 256, 0, stream>>>(cur, wq, qb, (void*)qbuf);
    conv3_mfma<64,0><<<1024, 256, 0, stream>>>(cur, wA1, off1b, o1buf);
    conv3_mfma<96,1><<<1024, 384, 0, stream>>>(o1buf, wA2, off1b, offbuf);
    sample_attn_kernel<<<VV/64, 256, 0, stream>>>(qbuf, offbuf, vols, wo,
        outb, bng, bnb, bnm, bnv, out, 64 + call*64);
  }
}

// Round 7
// 439.545 us; speedup vs baseline: 7.5431x; 1.1569x over previous
//
#include <hip/hip_runtime.h>
#include <math.h>

#define DD 16
#define HH 64
#define WW 64
#define VV (DD*HH*WW)      // 65536
#define CC 64
#define NHEADS 4
#define NSAMP 8
#define HDIM 16

typedef unsigned int uint;
typedef unsigned short ushort;
typedef __attribute__((ext_vector_type(8))) short bf16x8;
typedef __attribute__((ext_vector_type(4))) float f32x4;

__device__ __forceinline__ float clampf(float v, float lo, float hi){ return fminf(fmaxf(v, lo), hi); }
__device__ __forceinline__ int imin(int a, int b){ return a < b ? a : b; }
__device__ __forceinline__ int imax(int a, int b){ return a > b ? a : b; }

// bf16 helpers (RNE)
__device__ __forceinline__ ushort f2bf(float f){
  uint u = __float_as_uint(f);
  uint r = (u + 0x7fffu + ((u>>16)&1u)) >> 16;
  return (ushort)r;
}
__device__ __forceinline__ uint packbf2(float a, float b){
  return (uint)f2bf(a) | ((uint)f2bf(b) << 16);
}
__device__ __forceinline__ float bflo(uint u){ return __uint_as_float(u << 16); }
__device__ __forceinline__ float bfhi(uint u){ return __uint_as_float(u & 0xffff0000u); }
__device__ __forceinline__ float bf2f(ushort u){ return __uint_as_float((uint)u << 16); }

__device__ __forceinline__ float dot8(uint4 k, const float* q){
  return q[0]*bflo(k.x)+q[1]*bfhi(k.x)+q[2]*bflo(k.y)+q[3]*bfhi(k.y)
       + q[4]*bflo(k.z)+q[5]*bfhi(k.z)+q[6]*bflo(k.w)+q[7]*bfhi(k.w);
}
__device__ __forceinline__ void acc8(uint4 u, float cw, float* val){
  val[0]+=cw*bflo(u.x); val[1]+=cw*bfhi(u.x);
  val[2]+=cw*bflo(u.y); val[3]+=cw*bfhi(u.y);
  val[4]+=cw*bflo(u.z); val[5]+=cw*bfhi(u.z);
  val[6]+=cw*bflo(u.w); val[7]+=cw*bfhi(u.w);
}

// ---- weight repacks ------------------------------------------------------
// 3x3x3 conv weights -> bf16 pairs in exact MFMA A-fragment order.
// step s: tap = s>>1, h = s&1, ci = h*32 + q*8 + j. lane=q*16+m holds A[co=g*16+m][8k]
__global__ void repack_wmfma(const float* __restrict__ w, uint* __restrict__ o, int MG){
  int U = blockIdx.x*256 + threadIdx.x;
  int total = 54*MG*256;
  if (U >= total) return;
  int j2 = U & 3;
  int m  = (U>>2) & 15;
  int q  = (U>>6) & 3;
  int rest = U >> 8;          // s*MG + g
  int g = rest % MG;
  int s = rest / MG;
  int tap = s >> 1, h = s & 1;
  int co = g*16 + m;
  int ci = h*32 + q*8 + j2*2;
  int base = co*1728 + ci*27 + tap;
  o[U] = packbf2(w[base], w[base + 27]);
}
// 1x1 conv weights [co][64ci] -> bf16 A-fragments: frag = ks*MT+mt
__global__ void repack_w1mfma(const float* __restrict__ w, uint* __restrict__ o, int MT){
  int U = blockIdx.x*256 + threadIdx.x;
  int total = 2*MT*256;
  if (U >= total) return;
  int j2 = U & 3;
  int lane = (U>>2) & 63;
  int frag = U >> 8;
  int mt = frag % MT;
  int ks = frag / MT;
  int q = lane >> 4, m = lane & 15;
  int co = mt*16 + m;
  int ci = ks*32 + q*8 + j2*2;
  o[U] = packbf2(w[co*CC + ci], w[co*CC + ci + 1]);
}

// ---- 1x1 conv via MFMA ---------------------------------------------------
// EPI 0: +bias, pack bf16 -> vols[head][y][x][z][32ch] (kv, CO=128, grid 1024)
// EPI 1: (acc+bias)*0.25 -> bf16 out[call][co][v]      (q,  CO=64, grid 2048)
template<int CO, int EPI>
__global__ __launch_bounds__(256) void conv1_mfma(
    const float* __restrict__ xa, const float* __restrict__ xb,
    const uint* __restrict__ wA, const float* __restrict__ bias,
    void* __restrict__ outp)
{
  constexpr int MT = CO/16;
  constexpr int MW = MT/4;
  __shared__ ushort xt[64*72];    // 9216 B
  int tid = threadIdx.x;
  int lane = tid & 63;
  int g = __builtin_amdgcn_readfirstlane(tid >> 6);
  int q = lane >> 4, n = lane & 15;
  int call = blockIdx.x >> 10;
  int v0 = (blockIdx.x & 1023) * 64;
  const float* x = call ? xb : xa;
  for (int it = tid; it < 64*32; it += 256){
    int vox = it & 63; int cp = it >> 6;    // ci pair
    float a = x[(size_t)(2*cp)*VV + v0 + vox];
    float b = x[(size_t)(2*cp+1)*VV + v0 + vox];
    *reinterpret_cast<uint*>(&xt[vox*72 + 2*cp]) = packbf2(a,b);
  }
  __syncthreads();
  f32x4 acc[MW][4];
  #pragma unroll
  for (int mw=0;mw<MW;mw++)
    #pragma unroll
    for (int nt=0;nt<4;nt++){ acc[mw][nt].x=0.f; acc[mw][nt].y=0.f; acc[mw][nt].z=0.f; acc[mw][nt].w=0.f; }
  const char* ldsb = reinterpret_cast<const char*>(xt);
  const char* wac  = reinterpret_cast<const char*>(wA);
  #pragma unroll
  for (int ks=0; ks<2; ks++){
    bf16x8 bfr[4];
    #pragma unroll
    for (int nt=0; nt<4; nt++)
      bfr[nt] = *reinterpret_cast<const bf16x8*>(ldsb + ((nt*16+n)*144 + q*16 + ks*64));
    #pragma unroll
    for (int mw=0; mw<MW; mw++){
      int mt = g*MW + mw;
      bf16x8 af = *reinterpret_cast<const bf16x8*>(wac + (size_t)((ks*MT + mt)*64 + lane)*16);
      #pragma unroll
      for (int nt=0; nt<4; nt++)
        acc[mw][nt] = __builtin_amdgcn_mfma_f32_16x16x32_bf16(af, bfr[nt], acc[mw][nt], 0, 0, 0);
    }
  }
  #pragma unroll
  for (int mw=0; mw<MW; mw++){
    int mt = g*MW + mw;
    int cob = mt*16 + q*4;
    #pragma unroll
    for (int nt=0; nt<4; nt++){
      int v = v0 + nt*16 + n;
      float r0 = acc[mw][nt].x + bias[cob+0];
      float r1 = acc[mw][nt].y + bias[cob+1];
      float r2 = acc[mw][nt].z + bias[cob+2];
      float r3 = acc[mw][nt].w + bias[cob+3];
      if (EPI == 0){
        int z = v >> 12, y = (v >> 6) & 63, xx = v & 63;
        int head = cob >> 5;
        uint* vols = (uint*)outp;
        uint2 pk; pk.x = packbf2(r0,r1); pk.y = packbf2(r2,r3);
        *reinterpret_cast<uint2*>(vols + ((size_t)head*VV + (size_t)(y*WW+xx)*DD + z)*16 + ((cob&31)>>1)) = pk;
      } else {
        ushort* ob = (ushort*)outp + (size_t)call*CC*VV;
        ob[(size_t)(cob+0)*VV + v] = f2bf(r0*0.25f);
        ob[(size_t)(cob+1)*VV + v] = f2bf(r1*0.25f);
        ob[(size_t)(cob+2)*VV + v] = f2bf(r2*0.25f);
        ob[(size_t)(cob+3)*VV + v] = f2bf(r3*0.25f);
      }
    }
  }
}

// ---- 3x3x3 conv via implicit-GEMM MFMA, batched over 2 calls -------------
// 256 threads; wave w: m-tiles (w&1)*MROW.., n-tiles (w>>1)*2.. (MROW=CO/32)
// LDS: one ci-half (32 ci) of the 3x10x10 halo; two phases. Row stride 80B
// (conflict-free for b128). INPK: input is packed bf16 pairs [cp][v].
// OUTPK 1: gelu -> packed bf16 pairs. OUTPK 0: tanh -> bf16 planes.
template<int CO, int INPK, int OUTPK>
__global__ __launch_bounds__(256) void conv3_mfma(
    const float* __restrict__ xa, const float* __restrict__ xb,
    const uint* __restrict__ xpk,
    const uint* __restrict__ wA, const float* __restrict__ bias,
    void* __restrict__ outp)
{
  constexpr int MG = CO/16;
  constexpr int MROW = CO/32;
  __shared__ ushort xh[300*40];   // 24 KB
  int tid = threadIdx.x;
  int lane = tid & 63;
  int w = __builtin_amdgcn_readfirstlane(tid >> 6);
  int q = lane >> 4, n = lane & 15;
  int bid = blockIdx.x;           // 0..2047
  int xcd = bid & 7, islot = bid >> 3;
  int call = islot >> 7;
  int z = xcd*2 + ((islot >> 6) & 1);
  int rem = islot & 63;
  int by = (rem >> 3) << 3, bx = (rem & 7) << 3;

  const float* xin = call ? xb : xa;
  const uint* xinp = xpk + (size_t)call*32*VV;

  int mbase = (w & 1) * MROW;
  int np = w >> 1;
  int lo[2];
  #pragma unroll
  for (int nt=0;nt<2;nt++){
    int vox = (np*2+nt)*16 + n;
    lo[nt] = ((vox>>3)*10 + (vox&7))*80 + q*16;
  }
  f32x4 acc[MROW][2];
  #pragma unroll
  for (int mr=0;mr<MROW;mr++)
    #pragma unroll
    for (int nt=0;nt<2;nt++){ acc[mr][nt].x=0.f; acc[mr][nt].y=0.f; acc[mr][nt].z=0.f; acc[mr][nt].w=0.f; }

  const char* ldsb = reinterpret_cast<const char*>(xh);
  const char* wac  = reinterpret_cast<const char*>(wA);

  #pragma unroll 1
  for (int h=0; h<2; h++){
    if (h) __syncthreads();           // all waves done reading phase 0
    // stage ci-half h: 300 pos x 32 ci (8 groups of 4)
    for (int it = tid; it < 2400; it += 256){
      int cg = it / 300; int pos = it - cg*300;
      int dz = pos/100; int r = pos - dz*100; int dy = r/10; int dxx = r - dy*10;
      int gz = z + dz - 1, gy = by + dy - 1, gx = bx + dxx - 1;
      bool ok = (gz>=0 && gz<DD && gy>=0 && gy<HH && gx>=0 && gx<WW);
      uint2 pk; pk.x = 0u; pk.y = 0u;
      if (ok){
        size_t gv = (size_t)((gz*HH+gy)*WW + gx);
        if (INPK){
          int cp0 = h*16 + cg*2;
          pk.x = xinp[(size_t)cp0*VV + gv];
          pk.y = xinp[(size_t)(cp0+1)*VV + gv];
        } else {
          int ci0 = h*32 + cg*4;
          float v0 = xin[(size_t)(ci0  )*VV + gv];
          float v1 = xin[(size_t)(ci0+1)*VV + gv];
          float v2 = xin[(size_t)(ci0+2)*VV + gv];
          float v3 = xin[(size_t)(ci0+3)*VV + gv];
          pk.x = packbf2(v0,v1); pk.y = packbf2(v2,v3);
        }
      }
      *reinterpret_cast<uint2*>(&xh[pos*40 + cg*4]) = pk;
    }
    __syncthreads();
    #pragma unroll 3
    for (int tap=0; tap<27; tap++){
      int dz = tap/9; int r9 = tap - dz*9; int dy = r9/3; int dxx = r9 - dy*3;
      int stepOff = (dz*100 + dy*10 + dxx)*80;
      int s = tap*2 + h;
      bf16x8 af[MROW];
      #pragma unroll
      for (int mr=0;mr<MROW;mr++)
        af[mr] = *reinterpret_cast<const bf16x8*>(wac + (size_t)((s*MG + mbase+mr)*64 + lane)*16);
      bf16x8 bf[2];
      #pragma unroll
      for (int nt=0;nt<2;nt++)
        bf[nt] = *reinterpret_cast<const bf16x8*>(ldsb + (lo[nt] + stepOff));
      #pragma unroll
      for (int mr=0;mr<MROW;mr++)
        #pragma unroll
        for (int nt=0;nt<2;nt++)
          acc[mr][nt] = __builtin_amdgcn_mfma_f32_16x16x32_bf16(af[mr], bf[nt], acc[mr][nt], 0, 0, 0);
    }
  }

  // epilogue: C/D col = n (voxel), row = q*4+rr (co)
  #pragma unroll
  for (int mr=0; mr<MROW; mr++){
    int cob = (mbase+mr)*16 + q*4;
    #pragma unroll
    for (int nt=0; nt<2; nt++){
      int vox = (np*2+nt)*16 + n;
      int vy = by + (vox>>3), vx = bx + (vox&7);
      size_t gv = (size_t)((z*HH + vy)*WW + vx);
      float r0 = acc[mr][nt].x, r1 = acc[mr][nt].y, r2 = acc[mr][nt].z, r3 = acc[mr][nt].w;
      if (OUTPK == 1){
        r0 += bias[cob+0]; r1 += bias[cob+1]; r2 += bias[cob+2]; r3 += bias[cob+3];
        r0 = 0.5f*r0*(1.f + erff(r0*0.70710678118654752f));
        r1 = 0.5f*r1*(1.f + erff(r1*0.70710678118654752f));
        r2 = 0.5f*r2*(1.f + erff(r2*0.70710678118654752f));
        r3 = 0.5f*r3*(1.f + erff(r3*0.70710678118654752f));
        uint* dst = (uint*)outp + (size_t)call*32*VV;
        dst[(size_t)(cob>>1)*VV + gv]     = packbf2(r0,r1);
        dst[(size_t)((cob>>1)+1)*VV + gv] = packbf2(r2,r3);
      } else {
        ushort* dst = (ushort*)outp + (size_t)call*96*VV;
        dst[(size_t)(cob+0)*VV + gv] = f2bf(tanhf(r0));
        dst[(size_t)(cob+1)*VV + gv] = f2bf(tanhf(r1));
        dst[(size_t)(cob+2)*VV + gv] = f2bf(tanhf(r2));
        dst[(size_t)(cob+3)*VV + gv] = f2bf(tanhf(r3));
      }
    }
  }
}

// ---- sampling geometry (replicates the reference's channel->axis swap) ---
struct Geom { int x0,x1,y0,y1,z0,z1; float wx,wy,wz; };
__device__ __forceinline__ Geom make_geom(float zb, float yb, float xb,
                                          float o0, float o1, float o2){
  float g0 = clampf(zb + o0*(1.f/16.f), -1.f, 1.f);
  float g1 = clampf(yb + o1*(1.f/64.f), -1.f, 1.f);
  float g2 = clampf(xb + o2*(1.f/64.f), -1.f, 1.f);
  float ix = (g0+1.f)*0.5f*63.f;
  float iy = (g1+1.f)*0.5f*63.f;
  float iz = (g2+1.f)*0.5f*15.f;
  float fx=floorf(ix), fy=floorf(iy), fz=floorf(iz);
  Geom g;
  g.wx = ix-fx; g.wy = iy-fy; g.wz = iz-fz;
  g.x0 = imin(imax((int)fx,0), WW-1); g.x1 = imin(g.x0+1, WW-1);
  g.y0 = imin(imax((int)fy,0), HH-1); g.y1 = imin(g.y0+1, HH-1);
  g.z0 = imin(imax((int)fz,0), DD-1); g.z1 = imin(g.z0+1, DD-1);
  return g;
}

// ---- sample + attention (online softmax) + MFMA out conv + BN + relu -----
// batched over both calls: grid 2048 blocks of 64 voxels x 4 heads
__global__ __launch_bounds__(256) void sample_attn_kernel(
    const ushort* __restrict__ qbuf, const ushort* __restrict__ offbuf,
    const uint* __restrict__ vols, const uint* __restrict__ woA,
    const float* __restrict__ outb, const float* __restrict__ bng,
    const float* __restrict__ bnb, const float* __restrict__ bnm,
    const float* __restrict__ bnv, float* __restrict__ dout)
{
  __shared__ ushort fsb[64*72];   // fused attn output, bf16 [vox][ci], 144B rows
  int t = threadIdx.x;
  int lv = t & 63;
  int m = __builtin_amdgcn_readfirstlane(t >> 6);
  int bid = blockIdx.x;
  int xcd = bid & 7, islot = bid >> 3;
  int call = islot >> 7;
  int z = xcd*2 + ((islot >> 6) & 1);
  int y = islot & 63;
  int v0 = (z*HH + y)*WW;
  int v = v0 + lv;
  int x = lv;
  const ushort* qb = qbuf   + (size_t)call*CC*VV;
  const ushort* ob = offbuf + (size_t)call*96*VV;
  float zb = -1.f + (float)z*(2.f/15.f);
  float yb = -1.f + (float)y*(2.f/63.f);
  float xb = -1.f + (float)x*(2.f/63.f);
  float q[HDIM];
  #pragma unroll
  for (int c=0;c<HDIM;c++) q[c] = bf2f(qb[(size_t)(m*HDIM+c)*VV + v]);
  const uint* vol = vols + (size_t)m*VV*16;
  float mrun = -1e30f, lrun = 0.f;
  float fused[HDIM];
  #pragma unroll
  for (int c=0;c<HDIM;c++) fused[c]=0.f;
  #pragma unroll 2
  for (int s=0;s<NSAMP;s++){
    float o0 = bf2f(ob[(size_t)(m*24 + s*3 + 0)*VV + v]);
    float o1 = bf2f(ob[(size_t)(m*24 + s*3 + 1)*VV + v]);
    float o2 = bf2f(ob[(size_t)(m*24 + s*3 + 2)*VV + v]);
    Geom g = make_geom(zb,yb,xb,o0,o1,o2);
    float lg = 0.f;
    float val[HDIM];
    #pragma unroll
    for (int c=0;c<HDIM;c++) val[c]=0.f;
    #pragma unroll
    for (int ky=0;ky<2;ky++)
    #pragma unroll
    for (int kx=0;kx<2;kx++){
      int cy = ky? g.y1:g.y0, cx = kx? g.x1:g.x0;
      float wyx = (ky? g.wy : 1.f-g.wy)*(kx? g.wx : 1.f-g.wx);
      size_t base = (size_t)(cy*WW + cx)*DD;
      #pragma unroll
      for (int kz=0;kz<2;kz++){
        int cz = kz? g.z1:g.z0;
        float cw = wyx * (kz? g.wz : 1.f-g.wz);
        const uint4* cp = reinterpret_cast<const uint4*>(vol + (base + cz)*16);
        uint4 k0 = cp[0], k1 = cp[1];
        uint4 vv0 = cp[2], vv1 = cp[3];
        lg += cw*(dot8(k0, q) + dot8(k1, q+8));
        acc8(vv0, cw, val);
        acc8(vv1, cw, val+8);
      }
    }
    float mnew = fmaxf(mrun, lg);
    float sc = expf(mrun - mnew);
    float e  = expf(lg - mnew);
    lrun = lrun*sc + e;
    #pragma unroll
    for (int c=0;c<HDIM;c++) fused[c] = fused[c]*sc + e*val[c];
    mrun = mnew;
  }
  float isum = 1.f/lrun;
  #pragma unroll
  for (int c2=0;c2<8;c2++)
    *reinterpret_cast<uint*>(&fsb[lv*72 + m*HDIM + 2*c2]) =
        packbf2(fused[2*c2]*isum, fused[2*c2+1]*isum);
  __syncthreads();

  // out 1x1 conv via MFMA: wave m computes co-tile m (16 co) x 64 vox
  int lane = t & 63;
  int qq = lane >> 4, n = lane & 15;
  f32x4 acc[4];
  #pragma unroll
  for (int nt=0;nt<4;nt++){ acc[nt].x=0.f; acc[nt].y=0.f; acc[nt].z=0.f; acc[nt].w=0.f; }
  const char* ldsb = reinterpret_cast<const char*>(fsb);
  const char* wac  = reinterpret_cast<const char*>(woA);
  #pragma unroll
  for (int ks=0; ks<2; ks++){
    bf16x8 af = *reinterpret_cast<const bf16x8*>(wac + (size_t)((ks*4 + m)*64 + lane)*16);
    #pragma unroll
    for (int nt=0; nt<4; nt++){
      bf16x8 bf = *reinterpret_cast<const bf16x8*>(ldsb + ((nt*16+n)*144 + qq*16 + ks*64));
      acc[nt] = __builtin_amdgcn_mfma_f32_16x16x32_bf16(af, bf, acc[nt], 0, 0, 0);
    }
  }
  int choff = 64 + call*64;
  #pragma unroll
  for (int nt=0; nt<4; nt++){
    int vv = v0 + nt*16 + n;
    #pragma unroll
    for (int rr=0; rr<4; rr++){
      int co = m*16 + qq*4 + rr;
      float inv = rsqrtf(bnv[co] + 1e-5f) * bng[co];
      float val = (acc[nt][rr] + outb[co] - bnm[co]) * inv + bnb[co];
      val = fmaxf(val, 0.f);
      dout[(size_t)(choff+co)*VV + vv] = val;
    }
  }
}

extern "C" void kernel_launch(void* const* d_in, const int* in_sizes, int n_in,
                              void* d_out, int out_size, void* d_ws, size_t ws_size,
                              hipStream_t stream){
  (void)in_sizes; (void)n_in; (void)out_size; (void)ws_size;
  const float* mid  = (const float*)d_in[0];
  const float* occ  = (const float*)d_in[1];
  const float* prev = (const float*)d_in[2];
  const float* off1w= (const float*)d_in[3];
  const float* off1b= (const float*)d_in[4];
  const float* off2w= (const float*)d_in[5];
  const float* kvw  = (const float*)d_in[6];
  const float* kvb  = (const float*)d_in[7];
  const float* qw   = (const float*)d_in[8];
  const float* qb   = (const float*)d_in[9];
  const float* outw = (const float*)d_in[10];
  const float* outb = (const float*)d_in[11];
  const float* bng  = (const float*)d_in[12];
  const float* bnb  = (const float*)d_in[13];
  const float* bnm  = (const float*)d_in[14];
  const float* bnv  = (const float*)d_in[15];
  float* out = (float*)d_out;

  uint*   vols  = (uint*)d_ws;                          // 4*VV*16 uints   (16.8 MB)
  ushort* qbuf  = (ushort*)(vols + (size_t)4*VV*16);    // 2*64*VV ushort  (16.8 MB)
  uint*   o1pk  = (uint*)(qbuf + (size_t)2*CC*VV);      // 2*32*VV uint    (16.8 MB)
  ushort* offb  = (ushort*)(o1pk + (size_t)2*32*VV);    // 2*96*VV ushort  (25.2 MB)
  uint*   wA1   = (uint*)(offb + (size_t)2*96*VV);      // 55296
  uint*   wA2   = wA1 + 55296;                          // 82944
  uint*   wo    = wA2 + 82944;                          // 2048
  uint*   wkv   = wo  + 2048;                           // 4096
  uint*   wq    = wkv + 4096;                           // 2048

  repack_wmfma<<<(55296+255)/256, 256, 0, stream>>>(off1w, wA1, 4);
  repack_wmfma<<<(82944+255)/256, 256, 0, stream>>>(off2w, wA2, 6);
  repack_w1mfma<<<8, 256, 0, stream>>>(outw, wo, 4);
  repack_w1mfma<<<16, 256, 0, stream>>>(kvw, wkv, 8);
  repack_w1mfma<<<8, 256, 0, stream>>>(qw, wq, 4);
  conv1_mfma<128,0><<<1024, 256, 0, stream>>>(mid, mid, wkv, kvb, (void*)vols);
  hipMemcpyAsync(out, mid, (size_t)CC*VV*sizeof(float), hipMemcpyDeviceToDevice, stream);
  conv1_mfma<64,1><<<2048, 256, 0, stream>>>(occ, prev, wq, qb, (void*)qbuf);
  conv3_mfma<64,0,1><<<2048, 256, 0, stream>>>(occ, prev, (const uint*)nullptr, wA1, off1b, (void*)o1pk);
  conv3_mfma<96,1,0><<<2048, 256, 0, stream>>>((const float*)nullptr, (const float*)nullptr, o1pk, wA2, off1b, (void*)offb);
  sample_attn_kernel<<<2048, 256, 0, stream>>>(qbuf, offb, vols, wo,
      outb, bng, bnb, bnm, bnv, out);
}